// Round 7
// baseline (319.635 us; speedup 1.0000x reference)
//
#include <hip/hip_runtime.h>
#include <math.h>

#define BB 16
#define GG 512
#define PP 512
#define EE 256
#define HH 16
#define KD 16
#define HK 256

typedef __bf16 bf16x8 __attribute__((ext_vector_type(8)));
typedef __bf16 bf16x4 __attribute__((ext_vector_type(4)));
typedef float f32x4 __attribute__((ext_vector_type(4)));

__device__ inline void cvt_split8(const float* __restrict__ p, bf16x8& h, bf16x8& l)
{
    float4 f0 = *(const float4*)p;
    float4 f1 = *(const float4*)(p + 4);
    float v[8] = {f0.x, f0.y, f0.z, f0.w, f1.x, f1.y, f1.z, f1.w};
#pragma unroll
    for (int j = 0; j < 8; ++j) {
        __bf16 hh = (__bf16)v[j];
        h[j] = hh;
        l[j] = (__bf16)(v[j] - (float)hh);
    }
}

__device__ inline bf16x8 zero8()
{
    bf16x8 z;
#pragma unroll
    for (int j = 0; j < 8; ++j) z[j] = (__bf16)0.f;
    return z;
}

// ---------------------------------------------------------------------------
// Transpose + split W[Kd][N] fp32 -> Wt_hi/lo[N][Kd] bf16.
// ---------------------------------------------------------------------------
__global__ __launch_bounds__(256) void transpose_split(const float* __restrict__ W,
                                                       __bf16* __restrict__ th,
                                                       __bf16* __restrict__ tl,
                                                       int kbits, int N)
{
    const int id = blockIdx.x * 256 + threadIdx.x;
    const int Kd = 1 << kbits;
    const int k = id & (Kd - 1);
    const int n = id >> kbits;
    const float v = W[(size_t)k * N + n];
    const __bf16 h = (__bf16)v;
    th[((size_t)n << kbits) + k] = h;
    tl[((size_t)n << kbits) + k] = (__bf16)(v - (float)h);
}

// ---------------------------------------------------------------------------
// Split fp32 -> (hi, lo) bf16 pair (enc, for pointer head).
// ---------------------------------------------------------------------------
__global__ __launch_bounds__(256) void prep_split(const float* __restrict__ src,
                                                  __bf16* __restrict__ hi,
                                                  __bf16* __restrict__ lo)
{
    const int i = (blockIdx.x * 256 + threadIdx.x) * 4;
    float4 v = *(const float4*)(src + i);
    bf16x4 h, l;
    h[0] = (__bf16)v.x; l[0] = (__bf16)(v.x - (float)h[0]);
    h[1] = (__bf16)v.y; l[1] = (__bf16)(v.y - (float)h[1]);
    h[2] = (__bf16)v.z; l[2] = (__bf16)(v.z - (float)h[2]);
    h[3] = (__bf16)v.w; l[3] = (__bf16)(v.w - (float)h[3]);
    *(bf16x4*)(hi + i) = h;
    *(bf16x4*)(lo + i) = l;
}

// ---------------------------------------------------------------------------
// K projection, 32m x 64n tiles (1024 blocks = 4/CU): head-major bf16 hi/lo.
// ---------------------------------------------------------------------------
__global__ __launch_bounds__(256) void kproj_mfma(const float* __restrict__ A,
                                                  const __bf16* __restrict__ Bh,
                                                  const __bf16* __restrict__ Bl,
                                                  __bf16* __restrict__ Khi,
                                                  __bf16* __restrict__ Klo)
{
    const int t = threadIdx.x, lane = t & 63, w = t >> 6;
    const int m0 = blockIdx.y * 32 + (w >> 1) * 16;
    const int n0 = blockIdx.x * 64 + (w & 1) * 32;
    const int ln = lane & 15, kc = (lane >> 4) * 8;

    f32x4 acc[2];
    acc[0] = (f32x4){0.f, 0.f, 0.f, 0.f};
    acc[1] = (f32x4){0.f, 0.f, 0.f, 0.f};

    for (int k0 = 0; k0 < EE; k0 += 32) {
        bf16x8 ah, al, bh[2], bl[2];
        cvt_split8(A + (size_t)(m0 + ln) * EE + k0 + kc, ah, al);
#pragma unroll
        for (int nt = 0; nt < 2; ++nt) {
            const size_t o = (size_t)(n0 + nt * 16 + ln) * EE + k0 + kc;
            bh[nt] = *(const bf16x8*)(Bh + o);
            bl[nt] = *(const bf16x8*)(Bl + o);
        }
#pragma unroll
        for (int nt = 0; nt < 2; ++nt) {
            acc[nt] = __builtin_amdgcn_mfma_f32_16x16x32_bf16(ah, bh[nt], acc[nt], 0, 0, 0);
            acc[nt] = __builtin_amdgcn_mfma_f32_16x16x32_bf16(al, bh[nt], acc[nt], 0, 0, 0);
            acc[nt] = __builtin_amdgcn_mfma_f32_16x16x32_bf16(ah, bl[nt], acc[nt], 0, 0, 0);
        }
    }

    const int rbase = (lane >> 4) * 4;
#pragma unroll
    for (int nt = 0; nt < 2; ++nt)
#pragma unroll
        for (int r = 0; r < 4; ++r) {
            const int m = m0 + rbase + r;
            const int n = n0 + nt * 16 + ln;
            const int b = m >> 9, p = m & (PP - 1);
            const int hh = n >> 4, kk = n & 15;
            const float v = acc[nt][r];
            const __bf16 h = (__bf16)v;
            const size_t o = (((size_t)b * HH + hh) * PP + p) * KD + kk;
            Khi[o] = h;
            Klo[o] = (__bf16)(v - (float)h);
        }
}

// ---------------------------------------------------------------------------
// V projection, 32m x 64n tiles: TRANSPOSED bf16 [B,H,16k,P].
// ---------------------------------------------------------------------------
__global__ __launch_bounds__(256) void vproj_mfma(const float* __restrict__ A,
                                                  const __bf16* __restrict__ Bh,
                                                  const __bf16* __restrict__ Bl,
                                                  __bf16* __restrict__ Vt)
{
    const int t = threadIdx.x, lane = t & 63, w = t >> 6;
    const int m0 = blockIdx.y * 32 + (w >> 1) * 16;
    const int n0 = blockIdx.x * 64 + (w & 1) * 32;
    const int ln = lane & 15, kc = (lane >> 4) * 8;

    f32x4 acc[2];
    acc[0] = (f32x4){0.f, 0.f, 0.f, 0.f};
    acc[1] = (f32x4){0.f, 0.f, 0.f, 0.f};

    for (int k0 = 0; k0 < EE; k0 += 32) {
        bf16x8 ah, al, bh[2], bl[2];
        cvt_split8(A + (size_t)(m0 + ln) * EE + k0 + kc, ah, al);
#pragma unroll
        for (int nt = 0; nt < 2; ++nt) {
            const size_t o = (size_t)(n0 + nt * 16 + ln) * EE + k0 + kc;
            bh[nt] = *(const bf16x8*)(Bh + o);
            bl[nt] = *(const bf16x8*)(Bl + o);
        }
#pragma unroll
        for (int nt = 0; nt < 2; ++nt) {
            acc[nt] = __builtin_amdgcn_mfma_f32_16x16x32_bf16(ah, bh[nt], acc[nt], 0, 0, 0);
            acc[nt] = __builtin_amdgcn_mfma_f32_16x16x32_bf16(al, bh[nt], acc[nt], 0, 0, 0);
            acc[nt] = __builtin_amdgcn_mfma_f32_16x16x32_bf16(ah, bl[nt], acc[nt], 0, 0, 0);
        }
    }

    const int rbase = (lane >> 4) * 4;
#pragma unroll
    for (int nt = 0; nt < 2; ++nt)
#pragma unroll
        for (int r = 0; r < 4; ++r) {
            const int m = m0 + rbase + r;
            const int n = n0 + nt * 16 + ln;
            const int b = m >> 9, p = m & (PP - 1);
            const int hh = n >> 4, kk = n & 15;
            Vt[(((size_t)b * HH + hh) * KD + kk) * PP + p] = (__bf16)acc[nt][r];
        }
}

// ---------------------------------------------------------------------------
// Q projection, 32m x 64n tiles + rank-1 ct epilogue: bf16 hi/lo [B,H,G,16].
// ---------------------------------------------------------------------------
__global__ __launch_bounds__(256) void qproj_mfma(const float* __restrict__ in1,
                                                  const float* __restrict__ in2,
                                                  const float* __restrict__ ct,
                                                  const __bf16* __restrict__ Bh,
                                                  const __bf16* __restrict__ Bl,
                                                  const float* __restrict__ WqFull,
                                                  __bf16* __restrict__ Qhi,
                                                  __bf16* __restrict__ Qlo)
{
    const int t = threadIdx.x, lane = t & 63, w = t >> 6;
    const int m0 = blockIdx.y * 32 + (w >> 1) * 16;
    const int n0 = blockIdx.x * 64 + (w & 1) * 32;
    const int ln = lane & 15, kc = (lane >> 4) * 8;
    const int b = (blockIdx.y * 32) >> 9;
    const float* WqLast = WqFull + (size_t)512 * HK;

    f32x4 acc[2];
    acc[0] = (f32x4){0.f, 0.f, 0.f, 0.f};
    acc[1] = (f32x4){0.f, 0.f, 0.f, 0.f};

    for (int k0 = 0; k0 < 512; k0 += 32) {
        bf16x8 ah, al, bh[2], bl[2];
        const float* ap;
        if (k0 < 256)
            ap = in1 + (size_t)b * EE + k0 + kc;
        else
            ap = in2 + (size_t)(m0 + ln) * EE + (k0 - 256) + kc;
        cvt_split8(ap, ah, al);
#pragma unroll
        for (int nt = 0; nt < 2; ++nt) {
            const size_t o = ((size_t)(n0 + nt * 16 + ln) << 9) + k0 + kc;
            bh[nt] = *(const bf16x8*)(Bh + o);
            bl[nt] = *(const bf16x8*)(Bl + o);
        }
#pragma unroll
        for (int nt = 0; nt < 2; ++nt) {
            acc[nt] = __builtin_amdgcn_mfma_f32_16x16x32_bf16(ah, bh[nt], acc[nt], 0, 0, 0);
            acc[nt] = __builtin_amdgcn_mfma_f32_16x16x32_bf16(al, bh[nt], acc[nt], 0, 0, 0);
            acc[nt] = __builtin_amdgcn_mfma_f32_16x16x32_bf16(ah, bl[nt], acc[nt], 0, 0, 0);
        }
    }

    const int rbase = (lane >> 4) * 4;
#pragma unroll
    for (int nt = 0; nt < 2; ++nt)
#pragma unroll
        for (int r = 0; r < 4; ++r) {
            const int m = m0 + rbase + r;
            const int n = n0 + nt * 16 + ln;
            const int g = m & (GG - 1);
            const int hh = n >> 4, kk = n & 15;
            const float v = acc[nt][r] + ct[m] * WqLast[n];
            const __bf16 h = (__bf16)v;
            const size_t o = (((size_t)b * HH + hh) * GG + g) * KD + kk;
            Qhi[o] = h;
            Qlo[o] = (__bf16)(v - (float)h);
        }
}

// ---------------------------------------------------------------------------
// MFMA flash attention v6: one wave per (b, g-tile-16, head). Block = 4 waves
// = 4 heads of one head-quad; grid = (32 gtiles, 4 hq, 16 b) = 2048 blocks.
// No barriers, no cross-wave merge. Per wave: 4 p-chunks of 128; per chunk
// QK^T (split-bf16, k padded 16->32), exp (no max sub), P->per-wave LDS,
// PV MFMA accumulate. Mask read per-tile from global (L2-served).
// ---------------------------------------------------------------------------
__global__ __launch_bounds__(256) void attn_v6(const __bf16* __restrict__ Qhi,
                                               const __bf16* __restrict__ Qlo,
                                               const __bf16* __restrict__ Khi,
                                               const __bf16* __restrict__ Klo,
                                               const __bf16* __restrict__ Vt,
                                               const float* __restrict__ mask,
                                               float* __restrict__ Att)
{
    __shared__ __align__(16) __bf16 sP[4][16][136];

    const int t = threadIdx.x;
    const int lane = t & 63;
    const int w = __builtin_amdgcn_readfirstlane(t >> 6);
    const int g0 = blockIdx.x * 16;
    const int h = blockIdx.y * 4 + w;
    const int b = blockIdx.z;
    const int ln = lane & 15;
    const int quad = lane >> 4;
    const int kq = (quad & 1) * 8;   // real k-chunk for quads 0,1 (QK, k=16 pad 32)
    const int kq8 = quad * 8;        // k-chunk for PV (k-dim = p, all quads real)

    const size_t qbase = (((size_t)b * HH + h) * GG + g0) * KD;
    const size_t kbase = ((size_t)b * HH + h) * PP * KD;
    const size_t vbase = ((size_t)b * HH + h) * KD * PP;
    const float* mb = mask + ((size_t)(b * GG + g0 + quad * 4)) * PP;

    // Q A-fragments (row g = ln, k = quad*8+j; quads 2,3 zero-padded)
    bf16x8 qah = zero8(), qal = zero8();
    if (quad < 2) {
        qah = *(const bf16x8*)(Qhi + qbase + (size_t)ln * KD + kq);
        qal = *(const bf16x8*)(Qlo + qbase + (size_t)ln * KD + kq);
    }

    float rs[4] = {0.f, 0.f, 0.f, 0.f};
    f32x4 oacc = (f32x4){0.f, 0.f, 0.f, 0.f};

#pragma unroll
    for (int pc = 0; pc < 4; ++pc) {
        const int pbase = pc * 128;
#pragma unroll
        for (int tt = 0; tt < 8; ++tt) {
            bf16x8 kbh = zero8(), kbl = zero8();
            if (quad < 2) {
                const size_t o = kbase + (size_t)(pbase + tt * 16 + ln) * KD + kq;
                kbh = *(const bf16x8*)(Khi + o);
                kbl = *(const bf16x8*)(Klo + o);
            }
            f32x4 s = (f32x4){0.f, 0.f, 0.f, 0.f};
            s = __builtin_amdgcn_mfma_f32_16x16x32_bf16(qah, kbh, s, 0, 0, 0);
            s = __builtin_amdgcn_mfma_f32_16x16x32_bf16(qal, kbh, s, 0, 0, 0);
            s = __builtin_amdgcn_mfma_f32_16x16x32_bf16(qah, kbl, s, 0, 0, 0);
#pragma unroll
            for (int r = 0; r < 4; ++r) {
                const float e = __expf(s[r] * 0.25f + mb[(size_t)r * PP + pbase + tt * 16 + ln]);
                rs[r] += e;
                sP[w][quad * 4 + r][tt * 16 + ln] = (__bf16)e;
            }
        }
        // PV over this chunk (k-dim = 128 p -> 4 MFMAs); per-wave LDS, lockstep.
#pragma unroll
        for (int c = 0; c < 4; ++c) {
            bf16x8 pa = *(const bf16x8*)&sP[w][ln][c * 32 + kq8];
            bf16x8 vb = *(const bf16x8*)(Vt + vbase + (size_t)ln * PP + pbase + c * 32 + kq8);
            oacc = __builtin_amdgcn_mfma_f32_16x16x32_bf16(pa, vb, oacc, 0, 0, 0);
        }
    }

    // row-sum over the 16 p-columns (within each quad's 16 lanes)
#pragma unroll
    for (int r = 0; r < 4; ++r) {
#pragma unroll
        for (int mm = 1; mm < 16; mm <<= 1) rs[r] += __shfl_xor(rs[r], mm);
    }

    // write: row g = quad*4+r, col k = ln
#pragma unroll
    for (int r = 0; r < 4; ++r)
        Att[((size_t)(b * GG + g0 + quad * 4 + r)) * HK + h * KD + ln] = oacc[r] / rs[r];
}

// ---------------------------------------------------------------------------
// Output projection, 32m x 64n tiles -> bf16 hi/lo pair for pointer head.
// ---------------------------------------------------------------------------
__global__ __launch_bounds__(256) void outproj_mfma(const float* __restrict__ A,
                                                    const __bf16* __restrict__ Bh,
                                                    const __bf16* __restrict__ Bl,
                                                    const float* __restrict__ bias,
                                                    __bf16* __restrict__ Ch,
                                                    __bf16* __restrict__ Cl)
{
    const int t = threadIdx.x, lane = t & 63, w = t >> 6;
    const int m0 = blockIdx.y * 32 + (w >> 1) * 16;
    const int n0 = blockIdx.x * 64 + (w & 1) * 32;
    const int ln = lane & 15, kc = (lane >> 4) * 8;

    f32x4 acc[2];
    acc[0] = (f32x4){0.f, 0.f, 0.f, 0.f};
    acc[1] = (f32x4){0.f, 0.f, 0.f, 0.f};

    for (int k0 = 0; k0 < EE; k0 += 32) {
        bf16x8 ah, al, bh[2], bl[2];
        cvt_split8(A + (size_t)(m0 + ln) * EE + k0 + kc, ah, al);
#pragma unroll
        for (int nt = 0; nt < 2; ++nt) {
            const size_t o = (size_t)(n0 + nt * 16 + ln) * EE + k0 + kc;
            bh[nt] = *(const bf16x8*)(Bh + o);
            bl[nt] = *(const bf16x8*)(Bl + o);
        }
#pragma unroll
        for (int nt = 0; nt < 2; ++nt) {
            acc[nt] = __builtin_amdgcn_mfma_f32_16x16x32_bf16(ah, bh[nt], acc[nt], 0, 0, 0);
            acc[nt] = __builtin_amdgcn_mfma_f32_16x16x32_bf16(al, bh[nt], acc[nt], 0, 0, 0);
            acc[nt] = __builtin_amdgcn_mfma_f32_16x16x32_bf16(ah, bl[nt], acc[nt], 0, 0, 0);
        }
    }

    const int rbase = (lane >> 4) * 4;
#pragma unroll
    for (int nt = 0; nt < 2; ++nt)
#pragma unroll
        for (int r = 0; r < 4; ++r) {
            const int m = m0 + rbase + r;
            const int n = n0 + nt * 16 + ln;
            const float v = acc[nt][r] + bias[n];
            const __bf16 h = (__bf16)v;
            Ch[(size_t)m * HK + n] = h;
            Cl[(size_t)m * HK + n] = (__bf16)(v - (float)h);
        }
}

// ---------------------------------------------------------------------------
// Pointer head, 512-thread blocks (8 waves, 64 p each) for 16 waves/CU.
// ---------------------------------------------------------------------------
__global__ __launch_bounds__(512) void pointer_mfma(const __bf16* __restrict__ mh_hi,
                                                    const __bf16* __restrict__ mh_lo,
                                                    const __bf16* __restrict__ enc_hi,
                                                    const __bf16* __restrict__ enc_lo,
                                                    const float* __restrict__ mask,
                                                    float* __restrict__ out)
{
    __shared__ float sS[16][516];
    const int t = threadIdx.x;
    const int b = blockIdx.y, g0 = blockIdx.x * 16;
    const int lane = t & 63, w = t >> 6;   // 8 waves
    const int lm = lane & 15;
    const int kc = (lane >> 4) * 8;

    const size_t arow = ((size_t)(b * GG + g0 + lm)) * EE + kc;
    const size_t brow = ((size_t)(b * PP + w * 64 + lm)) * EE + kc;

    f32x4 acc[4];
#pragma unroll
    for (int pt = 0; pt < 4; ++pt) acc[pt] = (f32x4){0.f, 0.f, 0.f, 0.f};

    for (int k0 = 0; k0 < EE; k0 += 32) {
        bf16x8 ah = *(const bf16x8*)(mh_hi + arow + k0);
        bf16x8 al = *(const bf16x8*)(mh_lo + arow + k0);
#pragma unroll
        for (int pt = 0; pt < 4; ++pt) {
            const size_t bo = brow + (size_t)pt * 16 * EE + k0;
            bf16x8 bh = *(const bf16x8*)(enc_hi + bo);
            bf16x8 bl = *(const bf16x8*)(enc_lo + bo);
            acc[pt] = __builtin_amdgcn_mfma_f32_16x16x32_bf16(ah, bh, acc[pt], 0, 0, 0);
            acc[pt] = __builtin_amdgcn_mfma_f32_16x16x32_bf16(al, bh, acc[pt], 0, 0, 0);
            acc[pt] = __builtin_amdgcn_mfma_f32_16x16x32_bf16(ah, bl, acc[pt], 0, 0, 0);
        }
    }

    const int rbase = (lane >> 4) * 4;
#pragma unroll
    for (int pt = 0; pt < 4; ++pt) {
        const int p = w * 64 + pt * 16 + lm;
#pragma unroll
        for (int r = 0; r < 4; ++r)
            sS[rbase + r][p] = acc[pt][r] * 0.0625f;
    }
    __syncthreads();

    // softmax: 16 rows x 32 lanes each
    const int g = t >> 5, j = t & 31;
    const float* mrow = mask + (size_t)(b * GG + g0 + g) * PP;
    float mx = -1e30f;
#pragma unroll 4
    for (int ii = 0; ii < 16; ++ii) {
        const int p = j + (ii << 5);
        const float s = 10.f * tanhf(sS[g][p]) + mrow[p];
        sS[g][p] = s;
        mx = fmaxf(mx, s);
    }
#pragma unroll
    for (int mbit = 1; mbit < 32; mbit <<= 1) mx = fmaxf(mx, __shfl_xor(mx, mbit));
    float sum = 0.f;
#pragma unroll 4
    for (int ii = 0; ii < 16; ++ii) {
        const int p = j + (ii << 5);
        const float e = __expf(sS[g][p] - mx);
        sS[g][p] = e;
        sum += e;
    }
#pragma unroll
    for (int mbit = 1; mbit < 32; mbit <<= 1) sum += __shfl_xor(sum, mbit);
    const float inv = 1.f / sum;
    float* orow = out + (size_t)(b * GG + g0 + g) * PP;
#pragma unroll 4
    for (int ii = 0; ii < 16; ++ii) {
        const int p = j + (ii << 5);
        orow[p] = sS[g][p] * inv;
    }
}

// ---------------------------------------------------------------------------
extern "C" void kernel_launch(void* const* d_in, const int* in_sizes, int n_in,
                              void* d_out, int out_size, void* d_ws, size_t ws_size,
                              hipStream_t stream)
{
    const float* in1  = (const float*)d_in[0];
    const float* in2  = (const float*)d_in[1];
    const float* ct   = (const float*)d_in[2];
    const float* mask = (const float*)d_in[3];
    const float* enc  = (const float*)d_in[4];
    const float* Wq   = (const float*)d_in[5];
    const float* Wk   = (const float*)d_in[6];
    const float* Wv   = (const float*)d_in[7];
    const float* Wcw  = (const float*)d_in[8];
    const float* Wcb  = (const float*)d_in[9];
    float* out = (float*)d_out;
    float* ws  = (float*)d_ws;

    const size_t SEG = (size_t)BB * GG * HK;  // 2M elements
    __bf16* Khi = (__bf16*)ws;
    __bf16* Klo = Khi + SEG;
    __bf16* Vt  = (__bf16*)(ws + SEG);
    __bf16* Qhi = (__bf16*)(ws + 2 * SEG);
    __bf16* Qlo = Qhi + SEG;
    float*  Att = ws + 3 * SEG;
    __bf16* wkt_h = (__bf16*)Att;
    __bf16* wkt_l = wkt_h + 65536;
    __bf16* wvt_h = wkt_l + 65536;
    __bf16* wvt_l = wvt_h + 65536;
    __bf16* wqt_h = wvt_l + 65536;
    __bf16* wqt_l = wqt_h + 131072;
    __bf16* mh_h  = (__bf16*)ws;
    __bf16* mh_l  = mh_h + SEG;
    __bf16* enc_h = (__bf16*)(ws + SEG);
    __bf16* enc_l = enc_h + SEG;
    __bf16* wct_h = (__bf16*)(ws + 2 * SEG);
    __bf16* wct_l = wct_h + 65536;

    const dim3 blk(256);
    const dim3 pgrid(HK / 64, (BB * GG) / 32);  // (4, 256) = 1024 blocks

    transpose_split<<<dim3(256), blk, 0, stream>>>(Wk, wkt_h, wkt_l, 8, HK);
    transpose_split<<<dim3(256), blk, 0, stream>>>(Wv, wvt_h, wvt_l, 8, HK);
    transpose_split<<<dim3(512), blk, 0, stream>>>(Wq, wqt_h, wqt_l, 9, HK);

    kproj_mfma<<<pgrid, blk, 0, stream>>>(enc, wkt_h, wkt_l, Khi, Klo);
    vproj_mfma<<<pgrid, blk, 0, stream>>>(enc, wvt_h, wvt_l, Vt);
    qproj_mfma<<<pgrid, blk, 0, stream>>>(in1, in2, ct, wqt_h, wqt_l, Wq, Qhi, Qlo);

    attn_v6<<<dim3(GG / 16, HH / 4, BB), blk, 0, stream>>>(Qhi, Qlo, Khi, Klo, Vt, mask, Att);

    prep_split<<<dim3((BB * PP * EE) / 1024), blk, 0, stream>>>(enc, enc_h, enc_l);
    transpose_split<<<dim3(256), blk, 0, stream>>>(Wcw, wct_h, wct_l, 8, HK);
    outproj_mfma<<<pgrid, blk, 0, stream>>>(Att, wct_h, wct_l, Wcb, mh_h, mh_l);

    pointer_mfma<<<dim3(GG / 16, BB), dim3(512), 0, stream>>>(mh_h, mh_l, enc_h, enc_l, mask, out);
}

// Round 8
// 241.579 us; speedup vs baseline: 1.3231x; 1.3231x over previous
//
#include <hip/hip_runtime.h>
#include <math.h>

#define BB 16
#define GG 512
#define PP 512
#define EE 256
#define HH 16
#define KD 16
#define HK 256

typedef __bf16 bf16x8 __attribute__((ext_vector_type(8)));
typedef __bf16 bf16x4 __attribute__((ext_vector_type(4)));
typedef float f32x4 __attribute__((ext_vector_type(4)));
typedef float f32x16 __attribute__((ext_vector_type(16)));

__device__ inline void cvt_split8(const float* __restrict__ p, bf16x8& h, bf16x8& l)
{
    float4 f0 = *(const float4*)p;
    float4 f1 = *(const float4*)(p + 4);
    float v[8] = {f0.x, f0.y, f0.z, f0.w, f1.x, f1.y, f1.z, f1.w};
#pragma unroll
    for (int j = 0; j < 8; ++j) {
        __bf16 hh = (__bf16)v[j];
        h[j] = hh;
        l[j] = (__bf16)(v[j] - (float)hh);
    }
}

// ---------------------------------------------------------------------------
// All four weight transpose+splits in one launch.
// Wk/Wv/Wcw: [256][256] -> [n][k=256]; Wq: [513][256] -> [n][k=512] (row 512
// handled separately in qproj epilogue).
// ---------------------------------------------------------------------------
__global__ __launch_bounds__(256) void weight_prep(const float* __restrict__ Wk,
                                                   const float* __restrict__ Wv,
                                                   const float* __restrict__ Wq,
                                                   const float* __restrict__ Wc,
                                                   __bf16* __restrict__ wkt_h, __bf16* __restrict__ wkt_l,
                                                   __bf16* __restrict__ wvt_h, __bf16* __restrict__ wvt_l,
                                                   __bf16* __restrict__ wqt_h, __bf16* __restrict__ wqt_l,
                                                   __bf16* __restrict__ wct_h, __bf16* __restrict__ wct_l)
{
    int id = blockIdx.x * 256 + threadIdx.x;   // 0 .. 327679
    const float* W;
    __bf16 *th, *tl;
    int kbits;
    if (id < 65536)       { W = Wk; th = wkt_h; tl = wkt_l; kbits = 8; }
    else if (id < 131072) { id -= 65536;  W = Wv; th = wvt_h; tl = wvt_l; kbits = 8; }
    else if (id < 262144) { id -= 131072; W = Wq; th = wqt_h; tl = wqt_l; kbits = 9; }
    else                  { id -= 262144; W = Wc; th = wct_h; tl = wct_l; kbits = 8; }
    const int Kd = 1 << kbits;
    const int k = id & (Kd - 1);
    const int n = id >> kbits;
    const float v = W[(size_t)k * HK + n];
    const __bf16 h = (__bf16)v;
    th[((size_t)n << kbits) + k] = h;
    tl[((size_t)n << kbits) + k] = (__bf16)(v - (float)h);
}

// ---------------------------------------------------------------------------
// Fused K+V projection (64x64 tiles, 2x2 per wave): one pass over A (enc),
// K -> head-major bf16 hi/lo [B,H,P,16], V -> transposed bf16 [B,H,16,P].
// ---------------------------------------------------------------------------
__global__ __launch_bounds__(256, 2) void kvproj_mfma(const float* __restrict__ A,
                                                      const __bf16* __restrict__ Bkh,
                                                      const __bf16* __restrict__ Bkl,
                                                      const __bf16* __restrict__ Bvh,
                                                      const __bf16* __restrict__ Bvl,
                                                      __bf16* __restrict__ Khi,
                                                      __bf16* __restrict__ Klo,
                                                      __bf16* __restrict__ Vt)
{
    const int t = threadIdx.x, lane = t & 63, w = t >> 6;
    const int m0 = blockIdx.y * 64 + (w >> 1) * 32;
    const int n0 = blockIdx.x * 64 + (w & 1) * 32;
    const int ln = lane & 15, kc = (lane >> 4) * 8;

    f32x4 ak[2][2], av[2][2];
#pragma unroll
    for (int i = 0; i < 2; ++i)
#pragma unroll
        for (int j = 0; j < 2; ++j) {
            ak[i][j] = (f32x4){0.f, 0.f, 0.f, 0.f};
            av[i][j] = (f32x4){0.f, 0.f, 0.f, 0.f};
        }

    for (int k0 = 0; k0 < EE; k0 += 32) {
        bf16x8 ah[2], al[2];
#pragma unroll
        for (int mt = 0; mt < 2; ++mt)
            cvt_split8(A + (size_t)(m0 + mt * 16 + ln) * EE + k0 + kc, ah[mt], al[mt]);
#pragma unroll
        for (int nt = 0; nt < 2; ++nt) {
            const size_t o = (size_t)(n0 + nt * 16 + ln) * EE + k0 + kc;
            bf16x8 bkh = *(const bf16x8*)(Bkh + o);
            bf16x8 bkl = *(const bf16x8*)(Bkl + o);
            bf16x8 bvh = *(const bf16x8*)(Bvh + o);
            bf16x8 bvl = *(const bf16x8*)(Bvl + o);
#pragma unroll
            for (int mt = 0; mt < 2; ++mt) {
                ak[mt][nt] = __builtin_amdgcn_mfma_f32_16x16x32_bf16(ah[mt], bkh, ak[mt][nt], 0, 0, 0);
                ak[mt][nt] = __builtin_amdgcn_mfma_f32_16x16x32_bf16(al[mt], bkh, ak[mt][nt], 0, 0, 0);
                ak[mt][nt] = __builtin_amdgcn_mfma_f32_16x16x32_bf16(ah[mt], bkl, ak[mt][nt], 0, 0, 0);
                av[mt][nt] = __builtin_amdgcn_mfma_f32_16x16x32_bf16(ah[mt], bvh, av[mt][nt], 0, 0, 0);
                av[mt][nt] = __builtin_amdgcn_mfma_f32_16x16x32_bf16(al[mt], bvh, av[mt][nt], 0, 0, 0);
                av[mt][nt] = __builtin_amdgcn_mfma_f32_16x16x32_bf16(ah[mt], bvl, av[mt][nt], 0, 0, 0);
            }
        }
    }

    const int rbase = (lane >> 4) * 4;
#pragma unroll
    for (int mt = 0; mt < 2; ++mt)
#pragma unroll
        for (int nt = 0; nt < 2; ++nt)
#pragma unroll
            for (int r = 0; r < 4; ++r) {
                const int m = m0 + mt * 16 + rbase + r;
                const int n = n0 + nt * 16 + ln;
                const int b = m >> 9, p = m & (PP - 1);
                const int hh = n >> 4, kk = n & 15;
                const float vk = ak[mt][nt][r];
                const __bf16 hk = (__bf16)vk;
                const size_t ok = (((size_t)b * HH + hh) * PP + p) * KD + kk;
                Khi[ok] = hk;
                Klo[ok] = (__bf16)(vk - (float)hk);
                Vt[(((size_t)b * HH + hh) * KD + kk) * PP + p] = (__bf16)av[mt][nt][r];
            }
}

// ---------------------------------------------------------------------------
// Q projection (64x64, 2x2 per wave) + rank-1 ct epilogue: bf16 hi/lo [B,H,G,16].
// ---------------------------------------------------------------------------
__global__ __launch_bounds__(256) void qproj_mfma(const float* __restrict__ in1,
                                                  const float* __restrict__ in2,
                                                  const float* __restrict__ ct,
                                                  const __bf16* __restrict__ Bh,
                                                  const __bf16* __restrict__ Bl,
                                                  const float* __restrict__ WqFull,
                                                  __bf16* __restrict__ Qhi,
                                                  __bf16* __restrict__ Qlo)
{
    const int t = threadIdx.x, lane = t & 63, w = t >> 6;
    const int m0 = blockIdx.y * 64 + (w >> 1) * 32;
    const int n0 = blockIdx.x * 64 + (w & 1) * 32;
    const int ln = lane & 15, kc = (lane >> 4) * 8;
    const int b = (blockIdx.y * 64) >> 9;
    const float* WqLast = WqFull + (size_t)512 * HK;

    f32x4 acc[2][2];
#pragma unroll
    for (int i = 0; i < 2; ++i)
#pragma unroll
        for (int j = 0; j < 2; ++j) acc[i][j] = (f32x4){0.f, 0.f, 0.f, 0.f};

    for (int k0 = 0; k0 < 512; k0 += 32) {
        bf16x8 ah[2], al[2], bh[2], bl[2];
#pragma unroll
        for (int mt = 0; mt < 2; ++mt) {
            const float* ap;
            if (k0 < 256)
                ap = in1 + (size_t)b * EE + k0 + kc;
            else
                ap = in2 + (size_t)(m0 + mt * 16 + ln) * EE + (k0 - 256) + kc;
            cvt_split8(ap, ah[mt], al[mt]);
        }
#pragma unroll
        for (int nt = 0; nt < 2; ++nt) {
            const size_t o = ((size_t)(n0 + nt * 16 + ln) << 9) + k0 + kc;
            bh[nt] = *(const bf16x8*)(Bh + o);
            bl[nt] = *(const bf16x8*)(Bl + o);
        }
#pragma unroll
        for (int mt = 0; mt < 2; ++mt)
#pragma unroll
            for (int nt = 0; nt < 2; ++nt) {
                acc[mt][nt] = __builtin_amdgcn_mfma_f32_16x16x32_bf16(ah[mt], bh[nt], acc[mt][nt], 0, 0, 0);
                acc[mt][nt] = __builtin_amdgcn_mfma_f32_16x16x32_bf16(al[mt], bh[nt], acc[mt][nt], 0, 0, 0);
                acc[mt][nt] = __builtin_amdgcn_mfma_f32_16x16x32_bf16(ah[mt], bl[nt], acc[mt][nt], 0, 0, 0);
            }
    }

    const int rbase = (lane >> 4) * 4;
#pragma unroll
    for (int mt = 0; mt < 2; ++mt)
#pragma unroll
        for (int nt = 0; nt < 2; ++nt)
#pragma unroll
            for (int r = 0; r < 4; ++r) {
                const int m = m0 + mt * 16 + rbase + r;
                const int n = n0 + nt * 16 + ln;
                const int g = m & (GG - 1);
                const int hh = n >> 4, kk = n & 15;
                const float v = acc[mt][nt][r] + ct[m] * WqLast[n];
                const __bf16 h = (__bf16)v;
                const size_t o = (((size_t)b * HH + hh) * GG + g) * KD + kk;
                Qhi[o] = h;
                Qlo[o] = (__bf16)(v - (float)h);
            }
}

// ---------------------------------------------------------------------------
// attn_v8: one wave per (b, h, 32 g). QK via 32x32x16 MFMA (K=16 exact, no
// padding), sum-only flash softmax, P staged in per-wave LDS (row pad 40
// halfs -> only 2-way bank aliasing = free), PV via 2x 16x16x32 MFMA with
// B = Vt from global. No barriers. Output written as bf16 hi/lo split.
// ---------------------------------------------------------------------------
__global__ __launch_bounds__(256, 4) void attn_v8(const __bf16* __restrict__ Qhi,
                                                  const __bf16* __restrict__ Qlo,
                                                  const __bf16* __restrict__ Khi,
                                                  const __bf16* __restrict__ Klo,
                                                  const __bf16* __restrict__ Vt,
                                                  const float* __restrict__ mask,
                                                  __bf16* __restrict__ Ath,
                                                  __bf16* __restrict__ Atl)
{
    __shared__ __align__(16) __bf16 sP[4][32][40];
    __shared__ float srs[4][32];

    const int t = threadIdx.x;
    const int lane = t & 63;
    const int w = __builtin_amdgcn_readfirstlane(t >> 6);
    const int g0 = blockIdx.x * 32;
    const int h = blockIdx.y * 4 + w;
    const int b = blockIdx.z;
    const int ln32 = lane & 31;
    const int half = lane >> 5;
    const int ln16 = lane & 15;
    const int quad = (lane >> 4) & 3;

    const size_t qbase = (((size_t)b * HH + h) * GG + g0) * KD;
    const size_t kbase = ((size_t)b * HH + h) * PP * KD;
    const size_t vbase = ((size_t)b * HH + h) * KD * PP;
    const float* mbase = mask + ((size_t)(b * GG + g0)) * PP;

    // Q A-frag for 32x32x16: row m = lane&31, k = (lane>>5)*8 + j
    bf16x8 qah = *(const bf16x8*)(Qhi + qbase + (size_t)ln32 * KD + half * 8);
    bf16x8 qal = *(const bf16x8*)(Qlo + qbase + (size_t)ln32 * KD + half * 8);

    float rs[16];
#pragma unroll
    for (int r = 0; r < 16; ++r) rs[r] = 0.f;
    f32x4 o0 = (f32x4){0.f, 0.f, 0.f, 0.f};
    f32x4 o1 = (f32x4){0.f, 0.f, 0.f, 0.f};

#pragma unroll 2
    for (int pc = 0; pc < 16; ++pc) {
        const int pb = pc * 32;
        // K B-frag: row n(p) = lane&31, k = (lane>>5)*8 + j
        const size_t ko = kbase + (size_t)(pb + ln32) * KD + half * 8;
        bf16x8 kh = *(const bf16x8*)(Khi + ko);
        bf16x8 kl = *(const bf16x8*)(Klo + ko);

        f32x16 s = (f32x16){0.f, 0.f, 0.f, 0.f, 0.f, 0.f, 0.f, 0.f,
                            0.f, 0.f, 0.f, 0.f, 0.f, 0.f, 0.f, 0.f};
        s = __builtin_amdgcn_mfma_f32_32x32x16_bf16(qah, kh, s, 0, 0, 0);
        s = __builtin_amdgcn_mfma_f32_32x32x16_bf16(qal, kh, s, 0, 0, 0);
        s = __builtin_amdgcn_mfma_f32_32x32x16_bf16(qah, kl, s, 0, 0, 0);

        // exp + mask + stage into sP (C/D: col = lane&31 = p, row below)
#pragma unroll
        for (int r = 0; r < 16; ++r) {
            const int row = (r & 3) + 8 * (r >> 2) + 4 * half;
            const float m = mbase[(size_t)row * PP + pb + ln32];
            const float e = __expf(s[r] * 0.25f + m);
            rs[r] += e;
            sP[w][row][ln32] = (__bf16)e;
        }

        // PV on this 32-p chunk: B = Vt[n=head-k=ln16][k=p=quad*8+j]
        bf16x8 vb = *(const bf16x8*)(Vt + vbase + (size_t)ln16 * PP + pb + quad * 8);
        bf16x8 p0 = *(const bf16x8*)&sP[w][ln16][quad * 8];
        bf16x8 p1 = *(const bf16x8*)&sP[w][16 + ln16][quad * 8];
        o0 = __builtin_amdgcn_mfma_f32_16x16x32_bf16(p0, vb, o0, 0, 0, 0);
        o1 = __builtin_amdgcn_mfma_f32_16x16x32_bf16(p1, vb, o1, 0, 0, 0);
    }

    // reduce rs over the 32 p-lanes within each half (xor bits 0..4)
#pragma unroll
    for (int r = 0; r < 16; ++r) {
#pragma unroll
        for (int mm = 1; mm < 32; mm <<= 1) rs[r] += __shfl_xor(rs[r], mm);
    }
    if (ln32 == 0) {
#pragma unroll
        for (int r = 0; r < 16; ++r)
            srs[w][(r & 3) + 8 * (r >> 2) + 4 * half] = rs[r];
    }
    // intra-wave LDS dependency; lockstep wave needs no barrier

#pragma unroll
    for (int t2 = 0; t2 < 2; ++t2) {
        const f32x4 oc = t2 ? o1 : o0;
#pragma unroll
        for (int r = 0; r < 4; ++r) {
            const int grow = t2 * 16 + quad * 4 + r;
            const float v = oc[r] / srs[w][grow];
            const __bf16 hv = (__bf16)v;
            const size_t oo = ((size_t)(b * GG + g0 + grow)) * HK + h * KD + ln16;
            Ath[oo] = hv;
            Atl[oo] = (__bf16)(v - (float)hv);
        }
    }
}

// ---------------------------------------------------------------------------
// Output projection (64x64, 2x2): A = Att bf16 hi/lo (no cvt), -> mh hi/lo.
// ---------------------------------------------------------------------------
__global__ __launch_bounds__(256) void outproj_mfma(const __bf16* __restrict__ Ah,
                                                    const __bf16* __restrict__ Al,
                                                    const __bf16* __restrict__ Bh,
                                                    const __bf16* __restrict__ Bl,
                                                    const float* __restrict__ bias,
                                                    __bf16* __restrict__ Ch,
                                                    __bf16* __restrict__ Cl)
{
    const int t = threadIdx.x, lane = t & 63, w = t >> 6;
    const int m0 = blockIdx.y * 64 + (w >> 1) * 32;
    const int n0 = blockIdx.x * 64 + (w & 1) * 32;
    const int ln = lane & 15, kc = (lane >> 4) * 8;

    f32x4 acc[2][2];
#pragma unroll
    for (int i = 0; i < 2; ++i)
#pragma unroll
        for (int j = 0; j < 2; ++j) acc[i][j] = (f32x4){0.f, 0.f, 0.f, 0.f};

    for (int k0 = 0; k0 < EE; k0 += 32) {
        bf16x8 ah[2], al[2], bh[2], bl[2];
#pragma unroll
        for (int mt = 0; mt < 2; ++mt) {
            const size_t o = (size_t)(m0 + mt * 16 + ln) * EE + k0 + kc;
            ah[mt] = *(const bf16x8*)(Ah + o);
            al[mt] = *(const bf16x8*)(Al + o);
        }
#pragma unroll
        for (int nt = 0; nt < 2; ++nt) {
            const size_t o = (size_t)(n0 + nt * 16 + ln) * EE + k0 + kc;
            bh[nt] = *(const bf16x8*)(Bh + o);
            bl[nt] = *(const bf16x8*)(Bl + o);
        }
#pragma unroll
        for (int mt = 0; mt < 2; ++mt)
#pragma unroll
            for (int nt = 0; nt < 2; ++nt) {
                acc[mt][nt] = __builtin_amdgcn_mfma_f32_16x16x32_bf16(ah[mt], bh[nt], acc[mt][nt], 0, 0, 0);
                acc[mt][nt] = __builtin_amdgcn_mfma_f32_16x16x32_bf16(al[mt], bh[nt], acc[mt][nt], 0, 0, 0);
                acc[mt][nt] = __builtin_amdgcn_mfma_f32_16x16x32_bf16(ah[mt], bl[nt], acc[mt][nt], 0, 0, 0);
            }
    }

    const int rbase = (lane >> 4) * 4;
#pragma unroll
    for (int mt = 0; mt < 2; ++mt)
#pragma unroll
        for (int nt = 0; nt < 2; ++nt)
#pragma unroll
            for (int r = 0; r < 4; ++r) {
                const int m = m0 + mt * 16 + rbase + r;
                const int n = n0 + nt * 16 + ln;
                const float v = acc[mt][nt][r] + bias[n];
                const __bf16 h = (__bf16)v;
                Ch[(size_t)m * HK + n] = h;
                Cl[(size_t)m * HK + n] = (__bf16)(v - (float)h);
            }
}

// ---------------------------------------------------------------------------
// Pointer head (256 thr, wave owns 128 p): enc converted hi/lo on the fly.
// ---------------------------------------------------------------------------
__global__ __launch_bounds__(256) void pointer_mfma(const __bf16* __restrict__ mh_hi,
                                                    const __bf16* __restrict__ mh_lo,
                                                    const float* __restrict__ enc,
                                                    const float* __restrict__ mask,
                                                    float* __restrict__ out)
{
    __shared__ float sS[16][516];
    const int t = threadIdx.x;
    const int b = blockIdx.y, g0 = blockIdx.x * 16;
    const int lane = t & 63, w = t >> 6;
    const int lm = lane & 15;
    const int kc = (lane >> 4) * 8;

    const size_t arow = ((size_t)(b * GG + g0 + lm)) * EE + kc;
    const size_t brow = ((size_t)(b * PP + w * 128 + lm)) * EE + kc;

    f32x4 acc[8];
#pragma unroll
    for (int pt = 0; pt < 8; ++pt) acc[pt] = (f32x4){0.f, 0.f, 0.f, 0.f};

    for (int k0 = 0; k0 < EE; k0 += 32) {
        bf16x8 ah = *(const bf16x8*)(mh_hi + arow + k0);
        bf16x8 al = *(const bf16x8*)(mh_lo + arow + k0);
#pragma unroll
        for (int pt = 0; pt < 8; ++pt) {
            bf16x8 bh, bl;
            cvt_split8(enc + brow + (size_t)pt * 16 * EE + k0, bh, bl);
            acc[pt] = __builtin_amdgcn_mfma_f32_16x16x32_bf16(ah, bh, acc[pt], 0, 0, 0);
            acc[pt] = __builtin_amdgcn_mfma_f32_16x16x32_bf16(al, bh, acc[pt], 0, 0, 0);
            acc[pt] = __builtin_amdgcn_mfma_f32_16x16x32_bf16(ah, bl, acc[pt], 0, 0, 0);
        }
    }

    const int rbase = (lane >> 4) * 4;
#pragma unroll
    for (int pt = 0; pt < 8; ++pt) {
        const int p = w * 128 + pt * 16 + lm;
#pragma unroll
        for (int r = 0; r < 4; ++r)
            sS[rbase + r][p] = acc[pt][r] * 0.0625f;
    }
    __syncthreads();

    const int g = t >> 4, j = t & 15;
    const float* mrow = mask + (size_t)(b * GG + g0 + g) * PP;
    float mx = -1e30f;
#pragma unroll 4
    for (int ii = 0; ii < 32; ++ii) {
        const int p = j + (ii << 4);
        const float s = 10.f * tanhf(sS[g][p]) + mrow[p];
        sS[g][p] = s;
        mx = fmaxf(mx, s);
    }
#pragma unroll
    for (int mbit = 1; mbit < 16; mbit <<= 1) mx = fmaxf(mx, __shfl_xor(mx, mbit));
    float sum = 0.f;
#pragma unroll 4
    for (int ii = 0; ii < 32; ++ii) {
        const int p = j + (ii << 4);
        const float e = __expf(sS[g][p] - mx);
        sS[g][p] = e;
        sum += e;
    }
#pragma unroll
    for (int mbit = 1; mbit < 16; mbit <<= 1) sum += __shfl_xor(sum, mbit);
    const float inv = 1.f / sum;
    float* orow = out + (size_t)(b * GG + g0 + g) * PP;
#pragma unroll 4
    for (int ii = 0; ii < 32; ++ii) {
        const int p = j + (ii << 4);
        orow[p] = sS[g][p] * inv;
    }
}

// ---------------------------------------------------------------------------
extern "C" void kernel_launch(void* const* d_in, const int* in_sizes, int n_in,
                              void* d_out, int out_size, void* d_ws, size_t ws_size,
                              hipStream_t stream)
{
    const float* in1  = (const float*)d_in[0];
    const float* in2  = (const float*)d_in[1];
    const float* ct   = (const float*)d_in[2];
    const float* mask = (const float*)d_in[3];
    const float* enc  = (const float*)d_in[4];
    const float* Wq   = (const float*)d_in[5];
    const float* Wk   = (const float*)d_in[6];
    const float* Wv   = (const float*)d_in[7];
    const float* Wcw  = (const float*)d_in[8];
    const float* Wcb  = (const float*)d_in[9];
    float* out = (float*)d_out;
    float* ws  = (float*)d_ws;

    const size_t SEG = (size_t)BB * GG * HK;  // 2M elements; 32 MB total ws
    // R0 (8MB): K hi/lo; post-attn: mh hi/lo
    __bf16* Khi = (__bf16*)ws;
    __bf16* Klo = Khi + SEG;
    // R1 (8MB): Vt (4MB) + Att_hi (4MB)
    __bf16* Vt  = (__bf16*)(ws + SEG);
    __bf16* Ath = Vt + SEG;
    // R2 (8MB): Q hi/lo
    __bf16* Qhi = (__bf16*)(ws + 2 * SEG);
    __bf16* Qlo = Qhi + SEG;
    // R3 (8MB): weight splits (1.28MB) + Att_lo at +2MB (4MB)
    __bf16* wkt_h = (__bf16*)(ws + 3 * SEG);
    __bf16* wkt_l = wkt_h + 65536;
    __bf16* wvt_h = wkt_l + 65536;
    __bf16* wvt_l = wvt_h + 65536;
    __bf16* wqt_h = wvt_l + 65536;
    __bf16* wqt_l = wqt_h + 131072;
    __bf16* wct_h = wqt_l + 131072;
    __bf16* wct_l = wct_h + 65536;
    __bf16* Atl   = (__bf16*)(ws + 3 * SEG) + 1048576;  // R3 + 2MB
    // post-attn overlay:
    __bf16* mh_h  = (__bf16*)ws;
    __bf16* mh_l  = mh_h + SEG;

    const dim3 blk(256);
    const dim3 ggrid(HK / 64, (BB * GG) / 64);  // (4, 128) = 512 blocks

    weight_prep<<<dim3(1280), blk, 0, stream>>>(Wk, Wv, Wq, Wcw,
                                                wkt_h, wkt_l, wvt_h, wvt_l,
                                                wqt_h, wqt_l, wct_h, wct_l);

    kvproj_mfma<<<ggrid, blk, 0, stream>>>(enc, wkt_h, wkt_l, wvt_h, wvt_l, Khi, Klo, Vt);
    qproj_mfma<<<ggrid, blk, 0, stream>>>(in1, in2, ct, wqt_h, wqt_l, Wq, Qhi, Qlo);

    attn_v8<<<dim3(GG / 32, HH / 4, BB), blk, 0, stream>>>(Qhi, Qlo, Khi, Klo, Vt, mask, Ath, Atl);

    outproj_mfma<<<ggrid, blk, 0, stream>>>(Ath, Atl, wct_h, wct_l, Wcb, mh_h, mh_l);

    pointer_mfma<<<dim3(GG / 16, BB), blk, 0, stream>>>(mh_h, mh_l, enc, mask, out);
}

// Round 9
// 239.438 us; speedup vs baseline: 1.3349x; 1.0089x over previous
//
#include <hip/hip_runtime.h>
#include <math.h>

#define BB 16
#define GG 512
#define PP 512
#define EE 256
#define HH 16
#define KD 16
#define HK 256

typedef __bf16 bf16x8 __attribute__((ext_vector_type(8)));
typedef __bf16 bf16x4 __attribute__((ext_vector_type(4)));
typedef float f32x4 __attribute__((ext_vector_type(4)));
typedef float f32x16 __attribute__((ext_vector_type(16)));

__device__ inline void cvt_split8(const float* __restrict__ p, bf16x8& h, bf16x8& l)
{
    float4 f0 = *(const float4*)p;
    float4 f1 = *(const float4*)(p + 4);
    float v[8] = {f0.x, f0.y, f0.z, f0.w, f1.x, f1.y, f1.z, f1.w};
#pragma unroll
    for (int j = 0; j < 8; ++j) {
        __bf16 hh = (__bf16)v[j];
        h[j] = hh;
        l[j] = (__bf16)(v[j] - (float)hh);
    }
}

// ---------------------------------------------------------------------------
// All four weight transpose+splits in one launch.
// ---------------------------------------------------------------------------
__global__ __launch_bounds__(256) void weight_prep(const float* __restrict__ Wk,
                                                   const float* __restrict__ Wv,
                                                   const float* __restrict__ Wq,
                                                   const float* __restrict__ Wc,
                                                   __bf16* __restrict__ wkt_h, __bf16* __restrict__ wkt_l,
                                                   __bf16* __restrict__ wvt_h, __bf16* __restrict__ wvt_l,
                                                   __bf16* __restrict__ wqt_h, __bf16* __restrict__ wqt_l,
                                                   __bf16* __restrict__ wct_h, __bf16* __restrict__ wct_l)
{
    int id = blockIdx.x * 256 + threadIdx.x;   // 0 .. 327679
    const float* W;
    __bf16 *th, *tl;
    int kbits;
    if (id < 65536)       { W = Wk; th = wkt_h; tl = wkt_l; kbits = 8; }
    else if (id < 131072) { id -= 65536;  W = Wv; th = wvt_h; tl = wvt_l; kbits = 8; }
    else if (id < 262144) { id -= 131072; W = Wq; th = wqt_h; tl = wqt_l; kbits = 9; }
    else                  { id -= 262144; W = Wc; th = wct_h; tl = wct_l; kbits = 8; }
    const int Kd = 1 << kbits;
    const int k = id & (Kd - 1);
    const int n = id >> kbits;
    const float v = W[(size_t)k * HK + n];
    const __bf16 h = (__bf16)v;
    th[((size_t)n << kbits) + k] = h;
    tl[((size_t)n << kbits) + k] = (__bf16)(v - (float)h);
}

// ---------------------------------------------------------------------------
// Role bodies for the fused projection dispatch.
// ---------------------------------------------------------------------------
__device__ inline void kvproj_body(int bx, int tid,
                                   const float* __restrict__ A,
                                   const __bf16* __restrict__ Bkh,
                                   const __bf16* __restrict__ Bkl,
                                   const __bf16* __restrict__ Bvh,
                                   const __bf16* __restrict__ Bvl,
                                   __bf16* __restrict__ Khi,
                                   __bf16* __restrict__ Klo,
                                   __bf16* __restrict__ Vt)
{
    const int lane = tid & 63, w = tid >> 6;
    const int m0 = (bx >> 2) * 64 + (w >> 1) * 32;
    const int n0 = (bx & 3) * 64 + (w & 1) * 32;
    const int ln = lane & 15, kc = (lane >> 4) * 8;

    f32x4 ak[2][2], av[2][2];
#pragma unroll
    for (int i = 0; i < 2; ++i)
#pragma unroll
        for (int j = 0; j < 2; ++j) {
            ak[i][j] = (f32x4){0.f, 0.f, 0.f, 0.f};
            av[i][j] = (f32x4){0.f, 0.f, 0.f, 0.f};
        }

    for (int k0 = 0; k0 < EE; k0 += 32) {
        bf16x8 ah[2], al[2];
#pragma unroll
        for (int mt = 0; mt < 2; ++mt)
            cvt_split8(A + (size_t)(m0 + mt * 16 + ln) * EE + k0 + kc, ah[mt], al[mt]);
#pragma unroll
        for (int nt = 0; nt < 2; ++nt) {
            const size_t o = (size_t)(n0 + nt * 16 + ln) * EE + k0 + kc;
            bf16x8 bkh = *(const bf16x8*)(Bkh + o);
            bf16x8 bkl = *(const bf16x8*)(Bkl + o);
            bf16x8 bvh = *(const bf16x8*)(Bvh + o);
            bf16x8 bvl = *(const bf16x8*)(Bvl + o);
#pragma unroll
            for (int mt = 0; mt < 2; ++mt) {
                ak[mt][nt] = __builtin_amdgcn_mfma_f32_16x16x32_bf16(ah[mt], bkh, ak[mt][nt], 0, 0, 0);
                ak[mt][nt] = __builtin_amdgcn_mfma_f32_16x16x32_bf16(al[mt], bkh, ak[mt][nt], 0, 0, 0);
                ak[mt][nt] = __builtin_amdgcn_mfma_f32_16x16x32_bf16(ah[mt], bkl, ak[mt][nt], 0, 0, 0);
                av[mt][nt] = __builtin_amdgcn_mfma_f32_16x16x32_bf16(ah[mt], bvh, av[mt][nt], 0, 0, 0);
                av[mt][nt] = __builtin_amdgcn_mfma_f32_16x16x32_bf16(al[mt], bvh, av[mt][nt], 0, 0, 0);
                av[mt][nt] = __builtin_amdgcn_mfma_f32_16x16x32_bf16(ah[mt], bvl, av[mt][nt], 0, 0, 0);
            }
        }
    }

    const int rbase = (lane >> 4) * 4;
#pragma unroll
    for (int mt = 0; mt < 2; ++mt)
#pragma unroll
        for (int nt = 0; nt < 2; ++nt)
#pragma unroll
            for (int r = 0; r < 4; ++r) {
                const int m = m0 + mt * 16 + rbase + r;
                const int n = n0 + nt * 16 + ln;
                const int b = m >> 9, p = m & (PP - 1);
                const int hh = n >> 4, kk = n & 15;
                const float vk = ak[mt][nt][r];
                const __bf16 hk = (__bf16)vk;
                const size_t ok = (((size_t)b * HH + hh) * PP + p) * KD + kk;
                Khi[ok] = hk;
                Klo[ok] = (__bf16)(vk - (float)hk);
                Vt[(((size_t)b * HH + hh) * KD + kk) * PP + p] = (__bf16)av[mt][nt][r];
            }
}

__device__ inline void qproj_body(int bx, int tid,
                                  const float* __restrict__ in1,
                                  const float* __restrict__ in2,
                                  const float* __restrict__ ct,
                                  const __bf16* __restrict__ Bh,
                                  const __bf16* __restrict__ Bl,
                                  const float* __restrict__ WqFull,
                                  __bf16* __restrict__ Qhi,
                                  __bf16* __restrict__ Qlo)
{
    const int lane = tid & 63, w = tid >> 6;
    const int m0 = (bx >> 2) * 64 + (w >> 1) * 32;
    const int n0 = (bx & 3) * 64 + (w & 1) * 32;
    const int ln = lane & 15, kc = (lane >> 4) * 8;
    const int b = m0 >> 9;
    const float* WqLast = WqFull + (size_t)512 * HK;

    f32x4 acc[2][2];
#pragma unroll
    for (int i = 0; i < 2; ++i)
#pragma unroll
        for (int j = 0; j < 2; ++j) acc[i][j] = (f32x4){0.f, 0.f, 0.f, 0.f};

    for (int k0 = 0; k0 < 512; k0 += 32) {
        bf16x8 ah[2], al[2], bh[2], bl[2];
#pragma unroll
        for (int mt = 0; mt < 2; ++mt) {
            const float* ap;
            if (k0 < 256)
                ap = in1 + (size_t)b * EE + k0 + kc;
            else
                ap = in2 + (size_t)(m0 + mt * 16 + ln) * EE + (k0 - 256) + kc;
            cvt_split8(ap, ah[mt], al[mt]);
        }
#pragma unroll
        for (int nt = 0; nt < 2; ++nt) {
            const size_t o = ((size_t)(n0 + nt * 16 + ln) << 9) + k0 + kc;
            bh[nt] = *(const bf16x8*)(Bh + o);
            bl[nt] = *(const bf16x8*)(Bl + o);
        }
#pragma unroll
        for (int mt = 0; mt < 2; ++mt)
#pragma unroll
            for (int nt = 0; nt < 2; ++nt) {
                acc[mt][nt] = __builtin_amdgcn_mfma_f32_16x16x32_bf16(ah[mt], bh[nt], acc[mt][nt], 0, 0, 0);
                acc[mt][nt] = __builtin_amdgcn_mfma_f32_16x16x32_bf16(al[mt], bh[nt], acc[mt][nt], 0, 0, 0);
                acc[mt][nt] = __builtin_amdgcn_mfma_f32_16x16x32_bf16(ah[mt], bl[nt], acc[mt][nt], 0, 0, 0);
            }
    }

    const int rbase = (lane >> 4) * 4;
#pragma unroll
    for (int mt = 0; mt < 2; ++mt)
#pragma unroll
        for (int nt = 0; nt < 2; ++nt)
#pragma unroll
            for (int r = 0; r < 4; ++r) {
                const int m = m0 + mt * 16 + rbase + r;
                const int n = n0 + nt * 16 + ln;
                const int g = m & (GG - 1);
                const int hh = n >> 4, kk = n & 15;
                const float v = acc[mt][nt][r] + ct[m] * WqLast[n];
                const __bf16 h = (__bf16)v;
                const size_t o = (((size_t)b * HH + hh) * GG + g) * KD + kk;
                Qhi[o] = h;
                Qlo[o] = (__bf16)(v - (float)h);
            }
}

// ---------------------------------------------------------------------------
// Fused K/V + Q projections: 1024 blocks (4 blocks/CU) of mixed work.
// ---------------------------------------------------------------------------
__global__ __launch_bounds__(256, 2) void fused_proj(const float* __restrict__ enc,
                                                     const __bf16* __restrict__ Bkh,
                                                     const __bf16* __restrict__ Bkl,
                                                     const __bf16* __restrict__ Bvh,
                                                     const __bf16* __restrict__ Bvl,
                                                     __bf16* __restrict__ Khi,
                                                     __bf16* __restrict__ Klo,
                                                     __bf16* __restrict__ Vt,
                                                     const float* __restrict__ in1,
                                                     const float* __restrict__ in2,
                                                     const float* __restrict__ ct,
                                                     const __bf16* __restrict__ Bqh,
                                                     const __bf16* __restrict__ Bql,
                                                     const float* __restrict__ WqFull,
                                                     __bf16* __restrict__ Qhi,
                                                     __bf16* __restrict__ Qlo)
{
    const int id = blockIdx.x;
    if (id < 512)
        kvproj_body(id, threadIdx.x, enc, Bkh, Bkl, Bvh, Bvl, Khi, Klo, Vt);
    else
        qproj_body(id - 512, threadIdx.x, in1, in2, ct, Bqh, Bql, WqFull, Qhi, Qlo);
}

// ---------------------------------------------------------------------------
// attn_v8 (verified round 8): one wave per (b, h, 32 g); 32x32x16 QK,
// sum-only flash, per-wave LDS P staging, 16x16x32 PV; bf16 hi/lo output.
// ---------------------------------------------------------------------------
__global__ __launch_bounds__(256, 4) void attn_v8(const __bf16* __restrict__ Qhi,
                                                  const __bf16* __restrict__ Qlo,
                                                  const __bf16* __restrict__ Khi,
                                                  const __bf16* __restrict__ Klo,
                                                  const __bf16* __restrict__ Vt,
                                                  const float* __restrict__ mask,
                                                  __bf16* __restrict__ Ath,
                                                  __bf16* __restrict__ Atl)
{
    __shared__ __align__(16) __bf16 sP[4][32][40];
    __shared__ float srs[4][32];

    const int t = threadIdx.x;
    const int lane = t & 63;
    const int w = __builtin_amdgcn_readfirstlane(t >> 6);
    const int g0 = blockIdx.x * 32;
    const int h = blockIdx.y * 4 + w;
    const int b = blockIdx.z;
    const int ln32 = lane & 31;
    const int half = lane >> 5;
    const int ln16 = lane & 15;
    const int quad = (lane >> 4) & 3;

    const size_t qbase = (((size_t)b * HH + h) * GG + g0) * KD;
    const size_t kbase = ((size_t)b * HH + h) * PP * KD;
    const size_t vbase = ((size_t)b * HH + h) * KD * PP;
    const float* mbase = mask + ((size_t)(b * GG + g0)) * PP;

    bf16x8 qah = *(const bf16x8*)(Qhi + qbase + (size_t)ln32 * KD + half * 8);
    bf16x8 qal = *(const bf16x8*)(Qlo + qbase + (size_t)ln32 * KD + half * 8);

    float rs[16];
#pragma unroll
    for (int r = 0; r < 16; ++r) rs[r] = 0.f;
    f32x4 o0 = (f32x4){0.f, 0.f, 0.f, 0.f};
    f32x4 o1 = (f32x4){0.f, 0.f, 0.f, 0.f};

#pragma unroll 2
    for (int pc = 0; pc < 16; ++pc) {
        const int pb = pc * 32;
        const size_t ko = kbase + (size_t)(pb + ln32) * KD + half * 8;
        bf16x8 kh = *(const bf16x8*)(Khi + ko);
        bf16x8 kl = *(const bf16x8*)(Klo + ko);

        f32x16 s = (f32x16){0.f, 0.f, 0.f, 0.f, 0.f, 0.f, 0.f, 0.f,
                            0.f, 0.f, 0.f, 0.f, 0.f, 0.f, 0.f, 0.f};
        s = __builtin_amdgcn_mfma_f32_32x32x16_bf16(qah, kh, s, 0, 0, 0);
        s = __builtin_amdgcn_mfma_f32_32x32x16_bf16(qal, kh, s, 0, 0, 0);
        s = __builtin_amdgcn_mfma_f32_32x32x16_bf16(qah, kl, s, 0, 0, 0);

#pragma unroll
        for (int r = 0; r < 16; ++r) {
            const int row = (r & 3) + 8 * (r >> 2) + 4 * half;
            const float m = mbase[(size_t)row * PP + pb + ln32];
            const float e = __expf(s[r] * 0.25f + m);
            rs[r] += e;
            sP[w][row][ln32] = (__bf16)e;
        }

        bf16x8 vb = *(const bf16x8*)(Vt + vbase + (size_t)ln16 * PP + pb + quad * 8);
        bf16x8 p0 = *(const bf16x8*)&sP[w][ln16][quad * 8];
        bf16x8 p1 = *(const bf16x8*)&sP[w][16 + ln16][quad * 8];
        o0 = __builtin_amdgcn_mfma_f32_16x16x32_bf16(p0, vb, o0, 0, 0, 0);
        o1 = __builtin_amdgcn_mfma_f32_16x16x32_bf16(p1, vb, o1, 0, 0, 0);
    }

#pragma unroll
    for (int r = 0; r < 16; ++r) {
#pragma unroll
        for (int mm = 1; mm < 32; mm <<= 1) rs[r] += __shfl_xor(rs[r], mm);
    }
    if (ln32 == 0) {
#pragma unroll
        for (int r = 0; r < 16; ++r)
            srs[w][(r & 3) + 8 * (r >> 2) + 4 * half] = rs[r];
    }

#pragma unroll
    for (int t2 = 0; t2 < 2; ++t2) {
        const f32x4 oc = t2 ? o1 : o0;
#pragma unroll
        for (int r = 0; r < 4; ++r) {
            const int grow = t2 * 16 + quad * 4 + r;
            const float v = oc[r] / srs[w][grow];
            const __bf16 hv = (__bf16)v;
            const size_t oo = ((size_t)(b * GG + g0 + grow)) * HK + h * KD + ln16;
            Ath[oo] = hv;
            Atl[oo] = (__bf16)(v - (float)hv);
        }
    }
}

// ---------------------------------------------------------------------------
// Fused post-attention: outproj (512 blocks) + enc prep_split (2048 blocks).
// ---------------------------------------------------------------------------
__device__ inline void outproj_body(int bx, int tid,
                                    const __bf16* __restrict__ Ah,
                                    const __bf16* __restrict__ Al,
                                    const __bf16* __restrict__ Bh,
                                    const __bf16* __restrict__ Bl,
                                    const float* __restrict__ bias,
                                    __bf16* __restrict__ Ch,
                                    __bf16* __restrict__ Cl)
{
    const int lane = tid & 63, w = tid >> 6;
    const int m0 = (bx >> 2) * 64 + (w >> 1) * 32;
    const int n0 = (bx & 3) * 64 + (w & 1) * 32;
    const int ln = lane & 15, kc = (lane >> 4) * 8;

    f32x4 acc[2][2];
#pragma unroll
    for (int i = 0; i < 2; ++i)
#pragma unroll
        for (int j = 0; j < 2; ++j) acc[i][j] = (f32x4){0.f, 0.f, 0.f, 0.f};

    for (int k0 = 0; k0 < EE; k0 += 32) {
        bf16x8 ah[2], al[2], bh[2], bl[2];
#pragma unroll
        for (int mt = 0; mt < 2; ++mt) {
            const size_t o = (size_t)(m0 + mt * 16 + ln) * EE + k0 + kc;
            ah[mt] = *(const bf16x8*)(Ah + o);
            al[mt] = *(const bf16x8*)(Al + o);
        }
#pragma unroll
        for (int nt = 0; nt < 2; ++nt) {
            const size_t o = (size_t)(n0 + nt * 16 + ln) * EE + k0 + kc;
            bh[nt] = *(const bf16x8*)(Bh + o);
            bl[nt] = *(const bf16x8*)(Bl + o);
        }
#pragma unroll
        for (int mt = 0; mt < 2; ++mt)
#pragma unroll
            for (int nt = 0; nt < 2; ++nt) {
                acc[mt][nt] = __builtin_amdgcn_mfma_f32_16x16x32_bf16(ah[mt], bh[nt], acc[mt][nt], 0, 0, 0);
                acc[mt][nt] = __builtin_amdgcn_mfma_f32_16x16x32_bf16(al[mt], bh[nt], acc[mt][nt], 0, 0, 0);
                acc[mt][nt] = __builtin_amdgcn_mfma_f32_16x16x32_bf16(ah[mt], bl[nt], acc[mt][nt], 0, 0, 0);
            }
    }

    const int rbase = (lane >> 4) * 4;
#pragma unroll
    for (int mt = 0; mt < 2; ++mt)
#pragma unroll
        for (int nt = 0; nt < 2; ++nt)
#pragma unroll
            for (int r = 0; r < 4; ++r) {
                const int m = m0 + mt * 16 + rbase + r;
                const int n = n0 + nt * 16 + ln;
                const float v = acc[mt][nt][r] + bias[n];
                const __bf16 h = (__bf16)v;
                Ch[(size_t)m * HK + n] = h;
                Cl[(size_t)m * HK + n] = (__bf16)(v - (float)h);
            }
}

__global__ __launch_bounds__(256) void fused_post(const __bf16* __restrict__ Ah,
                                                  const __bf16* __restrict__ Al,
                                                  const __bf16* __restrict__ Bh,
                                                  const __bf16* __restrict__ Bl,
                                                  const float* __restrict__ bias,
                                                  __bf16* __restrict__ Ch,
                                                  __bf16* __restrict__ Cl,
                                                  const float* __restrict__ enc,
                                                  __bf16* __restrict__ enc_h,
                                                  __bf16* __restrict__ enc_l)
{
    const int id = blockIdx.x;
    if (id < 512) {
        outproj_body(id, threadIdx.x, Ah, Al, Bh, Bl, bias, Ch, Cl);
    } else {
        const int i = ((id - 512) * 256 + threadIdx.x) * 4;
        float4 v = *(const float4*)(enc + i);
        bf16x4 h, l;
        h[0] = (__bf16)v.x; l[0] = (__bf16)(v.x - (float)h[0]);
        h[1] = (__bf16)v.y; l[1] = (__bf16)(v.y - (float)h[1]);
        h[2] = (__bf16)v.z; l[2] = (__bf16)(v.z - (float)h[2]);
        h[3] = (__bf16)v.w; l[3] = (__bf16)(v.w - (float)h[3]);
        *(bf16x4*)(enc_h + i) = h;
        *(bf16x4*)(enc_l + i) = l;
    }
}

// ---------------------------------------------------------------------------
// Pointer head (round-6 verified form): pre-split enc, 4 waves x 128 p.
// ---------------------------------------------------------------------------
__global__ __launch_bounds__(256) void pointer_mfma(const __bf16* __restrict__ mh_hi,
                                                    const __bf16* __restrict__ mh_lo,
                                                    const __bf16* __restrict__ enc_hi,
                                                    const __bf16* __restrict__ enc_lo,
                                                    const float* __restrict__ mask,
                                                    float* __restrict__ out)
{
    __shared__ float sS[16][516];
    const int t = threadIdx.x;
    const int b = blockIdx.y, g0 = blockIdx.x * 16;
    const int lane = t & 63, w = t >> 6;
    const int lm = lane & 15;
    const int kc = (lane >> 4) * 8;

    const size_t arow = ((size_t)(b * GG + g0 + lm)) * EE + kc;
    const size_t brow = ((size_t)(b * PP + w * 128 + lm)) * EE + kc;

    f32x4 acc[8];
#pragma unroll
    for (int pt = 0; pt < 8; ++pt) acc[pt] = (f32x4){0.f, 0.f, 0.f, 0.f};

    for (int k0 = 0; k0 < EE; k0 += 32) {
        bf16x8 ah = *(const bf16x8*)(mh_hi + arow + k0);
        bf16x8 al = *(const bf16x8*)(mh_lo + arow + k0);
#pragma unroll
        for (int pt = 0; pt < 8; ++pt) {
            const size_t bo = brow + (size_t)pt * 16 * EE + k0;
            bf16x8 bh = *(const bf16x8*)(enc_hi + bo);
            bf16x8 bl = *(const bf16x8*)(enc_lo + bo);
            acc[pt] = __builtin_amdgcn_mfma_f32_16x16x32_bf16(ah, bh, acc[pt], 0, 0, 0);
            acc[pt] = __builtin_amdgcn_mfma_f32_16x16x32_bf16(al, bh, acc[pt], 0, 0, 0);
            acc[pt] = __builtin_amdgcn_mfma_f32_16x16x32_bf16(ah, bl, acc[pt], 0, 0, 0);
        }
    }

    const int rbase = (lane >> 4) * 4;
#pragma unroll
    for (int pt = 0; pt < 8; ++pt) {
        const int p = w * 128 + pt * 16 + lm;
#pragma unroll
        for (int r = 0; r < 4; ++r)
            sS[rbase + r][p] = acc[pt][r] * 0.0625f;
    }
    __syncthreads();

    const int g = t >> 4, j = t & 15;
    const float* mrow = mask + (size_t)(b * GG + g0 + g) * PP;
    float mx = -1e30f;
#pragma unroll 4
    for (int ii = 0; ii < 32; ++ii) {
        const int p = j + (ii << 4);
        const float s = 10.f * tanhf(sS[g][p]) + mrow[p];
        sS[g][p] = s;
        mx = fmaxf(mx, s);
    }
#pragma unroll
    for (int mbit = 1; mbit < 16; mbit <<= 1) mx = fmaxf(mx, __shfl_xor(mx, mbit));
    float sum = 0.f;
#pragma unroll 4
    for (int ii = 0; ii < 32; ++ii) {
        const int p = j + (ii << 4);
        const float e = __expf(sS[g][p] - mx);
        sS[g][p] = e;
        sum += e;
    }
#pragma unroll
    for (int mbit = 1; mbit < 16; mbit <<= 1) sum += __shfl_xor(sum, mbit);
    const float inv = 1.f / sum;
    float* orow = out + (size_t)(b * GG + g0 + g) * PP;
#pragma unroll 4
    for (int ii = 0; ii < 32; ++ii) {
        const int p = j + (ii << 4);
        orow[p] = sS[g][p] * inv;
    }
}

// ---------------------------------------------------------------------------
extern "C" void kernel_launch(void* const* d_in, const int* in_sizes, int n_in,
                              void* d_out, int out_size, void* d_ws, size_t ws_size,
                              hipStream_t stream)
{
    const float* in1  = (const float*)d_in[0];
    const float* in2  = (const float*)d_in[1];
    const float* ct   = (const float*)d_in[2];
    const float* mask = (const float*)d_in[3];
    const float* enc  = (const float*)d_in[4];
    const float* Wq   = (const float*)d_in[5];
    const float* Wk   = (const float*)d_in[6];
    const float* Wv   = (const float*)d_in[7];
    const float* Wcw  = (const float*)d_in[8];
    const float* Wcb  = (const float*)d_in[9];
    float* out = (float*)d_out;
    float* ws  = (float*)d_ws;

    const size_t SEG = (size_t)BB * GG * HK;  // 2M elements; 32 MB total ws
    // R0 (8MB): K hi/lo; post-attn: mh hi/lo
    __bf16* Khi = (__bf16*)ws;
    __bf16* Klo = Khi + SEG;
    // R1 (8MB): Vt (4MB) + Att_hi (4MB)
    __bf16* Vt  = (__bf16*)(ws + SEG);
    __bf16* Ath = Vt + SEG;
    // R2 (8MB): Q hi/lo; post-attn: enc hi/lo
    __bf16* Qhi = (__bf16*)(ws + 2 * SEG);
    __bf16* Qlo = Qhi + SEG;
    // R3 (8MB): weight splits (1.28MB) + Att_lo at +2MB (4MB)
    __bf16* wkt_h = (__bf16*)(ws + 3 * SEG);
    __bf16* wkt_l = wkt_h + 65536;
    __bf16* wvt_h = wkt_l + 65536;
    __bf16* wvt_l = wvt_h + 65536;
    __bf16* wqt_h = wvt_l + 65536;
    __bf16* wqt_l = wqt_h + 131072;
    __bf16* wct_h = wqt_l + 131072;
    __bf16* wct_l = wct_h + 65536;
    __bf16* Atl   = (__bf16*)(ws + 3 * SEG) + 1048576;
    // post-attn overlays:
    __bf16* mh_h  = (__bf16*)ws;
    __bf16* mh_l  = mh_h + SEG;
    __bf16* enc_h = (__bf16*)(ws + 2 * SEG);
    __bf16* enc_l = enc_h + SEG;

    const dim3 blk(256);

    weight_prep<<<dim3(1280), blk, 0, stream>>>(Wk, Wv, Wq, Wcw,
                                                wkt_h, wkt_l, wvt_h, wvt_l,
                                                wqt_h, wqt_l, wct_h, wct_l);

    fused_proj<<<dim3(1024), blk, 0, stream>>>(enc, wkt_h, wkt_l, wvt_h, wvt_l,
                                               Khi, Klo, Vt,
                                               in1, in2, ct, wqt_h, wqt_l, Wq,
                                               Qhi, Qlo);

    attn_v8<<<dim3(GG / 32, HH / 4, BB), blk, 0, stream>>>(Qhi, Qlo, Khi, Klo, Vt, mask, Ath, Atl);

    fused_post<<<dim3(2560), blk, 0, stream>>>(Ath, Atl, wct_h, wct_l, Wcb,
                                               mh_h, mh_l, enc, enc_h, enc_l);

    pointer_mfma<<<dim3(GG / 16, BB), blk, 0, stream>>>(mh_h, mh_l, enc_h, enc_l, mask, out);
}

// Round 10
// 220.966 us; speedup vs baseline: 1.4465x; 1.0836x over previous
//
#include <hip/hip_runtime.h>
#include <math.h>

#define BB 16
#define GG 512
#define PP 512
#define EE 256
#define HH 16
#define KD 16
#define HK 256

typedef __bf16 bf16x8 __attribute__((ext_vector_type(8)));
typedef __bf16 bf16x4 __attribute__((ext_vector_type(4)));
typedef float f32x4 __attribute__((ext_vector_type(4)));
typedef float f32x16 __attribute__((ext_vector_type(16)));

// LDS geometry for fused_proj (bytes): compute phase 30720, epilogue 29184.
#define SA_STRIDE 40           // 32 cols + 8 pad (80B rows: 16B-aligned, <=4-way banks)
#define SMEM_BYTES 30720

__device__ inline void cvt_split8(const float* __restrict__ p, bf16x8& h, bf16x8& l)
{
    float4 f0 = *(const float4*)p;
    float4 f1 = *(const float4*)(p + 4);
    float v[8] = {f0.x, f0.y, f0.z, f0.w, f1.x, f1.y, f1.z, f1.w};
#pragma unroll
    for (int j = 0; j < 8; ++j) {
        __bf16 hh = (__bf16)v[j];
        h[j] = hh;
        l[j] = (__bf16)(v[j] - (float)hh);
    }
}

// ---------------------------------------------------------------------------
// All four weight transpose+splits in one launch.
// ---------------------------------------------------------------------------
__global__ __launch_bounds__(256) void weight_prep(const float* __restrict__ Wk,
                                                   const float* __restrict__ Wv,
                                                   const float* __restrict__ Wq,
                                                   const float* __restrict__ Wc,
                                                   __bf16* __restrict__ wkt_h, __bf16* __restrict__ wkt_l,
                                                   __bf16* __restrict__ wvt_h, __bf16* __restrict__ wvt_l,
                                                   __bf16* __restrict__ wqt_h, __bf16* __restrict__ wqt_l,
                                                   __bf16* __restrict__ wct_h, __bf16* __restrict__ wct_l)
{
    int id = blockIdx.x * 256 + threadIdx.x;
    const float* W;
    __bf16 *th, *tl;
    int kbits;
    if (id < 65536)       { W = Wk; th = wkt_h; tl = wkt_l; kbits = 8; }
    else if (id < 131072) { id -= 65536;  W = Wv; th = wvt_h; tl = wvt_l; kbits = 8; }
    else if (id < 262144) { id -= 131072; W = Wq; th = wqt_h; tl = wqt_l; kbits = 9; }
    else                  { id -= 262144; W = Wc; th = wct_h; tl = wct_l; kbits = 8; }
    const int Kd = 1 << kbits;
    const int k = id & (Kd - 1);
    const int n = id >> kbits;
    const float v = W[(size_t)k * HK + n];
    const __bf16 h = (__bf16)v;
    th[((size_t)n << kbits) + k] = h;
    tl[((size_t)n << kbits) + k] = (__bf16)(v - (float)h);
}

// ---------------------------------------------------------------------------
// LDS-staged fused K/V projection body. Block = 64m x 64n, 4 waves (2x2 of
// 16-tiles each... wave w: m-half (w>>1)*32, n-half (w&1)*32).
// A staged coalesced fp32->bf16 hi/lo; B (4 weight mats) staged one per wave.
// Epilogue repacked through LDS for fully coalesced 16B global stores.
// ---------------------------------------------------------------------------
__device__ inline void kvproj_body(int bx, int tid, unsigned char* smem,
                                   const float* __restrict__ A,
                                   const __bf16* __restrict__ Bkh,
                                   const __bf16* __restrict__ Bkl,
                                   const __bf16* __restrict__ Bvh,
                                   const __bf16* __restrict__ Bvl,
                                   __bf16* __restrict__ Khi,
                                   __bf16* __restrict__ Klo,
                                   __bf16* __restrict__ Vt)
{
    __bf16* sAh = (__bf16*)smem;               // [64][SA_STRIDE]
    __bf16* sAl = sAh + 64 * SA_STRIDE;
    __bf16* sB  = sAl + 64 * SA_STRIDE;        // [4][64][SA_STRIDE]

    const int lane = tid & 63;
    const int w = __builtin_amdgcn_readfirstlane(tid >> 6);
    const int m0 = (bx >> 2) * 64;
    const int n0 = (bx & 3) * 64;
    const int wm = (w >> 1) * 32, wn = (w & 1) * 32;
    const int ln = lane & 15, kq = (lane >> 4) * 8;
    const int ar = tid >> 2, ac = (tid & 3) * 8;

    const __bf16* bsel = (w == 0) ? Bkh : (w == 1) ? Bkl : (w == 2) ? Bvh : Bvl;

    f32x4 ak[2][2], av[2][2];
#pragma unroll
    for (int i = 0; i < 2; ++i)
#pragma unroll
        for (int j = 0; j < 2; ++j) {
            ak[i][j] = (f32x4){0.f, 0.f, 0.f, 0.f};
            av[i][j] = (f32x4){0.f, 0.f, 0.f, 0.f};
        }

    for (int k0 = 0; k0 < EE; k0 += 32) {
        // stage A (coalesced 128B rows, cvt once per tile)
        {
            bf16x8 h8, l8;
            cvt_split8(A + (size_t)(m0 + ar) * EE + k0 + ac, h8, l8);
            *(bf16x8*)&sAh[ar * SA_STRIDE + ac] = h8;
            *(bf16x8*)&sAl[ar * SA_STRIDE + ac] = l8;
        }
        // stage B: wave w stages matrix w; lane = row (dense 64B line per row)
        {
            const __bf16* src = bsel + (size_t)(n0 + lane) * EE + k0;
            __bf16* dst = sB + (w * 64 + lane) * SA_STRIDE;
            *(bf16x8*)&dst[0]  = *(const bf16x8*)&src[0];
            *(bf16x8*)&dst[8]  = *(const bf16x8*)&src[8];
            *(bf16x8*)&dst[16] = *(const bf16x8*)&src[16];
            *(bf16x8*)&dst[24] = *(const bf16x8*)&src[24];
        }
        __syncthreads();

        bf16x8 ah[2], al[2];
#pragma unroll
        for (int mt = 0; mt < 2; ++mt) {
            ah[mt] = *(const bf16x8*)&sAh[(wm + mt * 16 + ln) * SA_STRIDE + kq];
            al[mt] = *(const bf16x8*)&sAl[(wm + mt * 16 + ln) * SA_STRIDE + kq];
        }
#pragma unroll
        for (int nt = 0; nt < 2; ++nt) {
            const int rowb = wn + nt * 16 + ln;
            bf16x8 bkh8 = *(const bf16x8*)&sB[(0 * 64 + rowb) * SA_STRIDE + kq];
            bf16x8 bkl8 = *(const bf16x8*)&sB[(1 * 64 + rowb) * SA_STRIDE + kq];
            bf16x8 bvh8 = *(const bf16x8*)&sB[(2 * 64 + rowb) * SA_STRIDE + kq];
            bf16x8 bvl8 = *(const bf16x8*)&sB[(3 * 64 + rowb) * SA_STRIDE + kq];
#pragma unroll
            for (int mt = 0; mt < 2; ++mt) {
                ak[mt][nt] = __builtin_amdgcn_mfma_f32_16x16x32_bf16(ah[mt], bkh8, ak[mt][nt], 0, 0, 0);
                ak[mt][nt] = __builtin_amdgcn_mfma_f32_16x16x32_bf16(al[mt], bkh8, ak[mt][nt], 0, 0, 0);
                ak[mt][nt] = __builtin_amdgcn_mfma_f32_16x16x32_bf16(ah[mt], bkl8, ak[mt][nt], 0, 0, 0);
                av[mt][nt] = __builtin_amdgcn_mfma_f32_16x16x32_bf16(ah[mt], bvh8, av[mt][nt], 0, 0, 0);
                av[mt][nt] = __builtin_amdgcn_mfma_f32_16x16x32_bf16(al[mt], bvh8, av[mt][nt], 0, 0, 0);
                av[mt][nt] = __builtin_amdgcn_mfma_f32_16x16x32_bf16(ah[mt], bvl8, av[mt][nt], 0, 0, 0);
            }
        }
        __syncthreads();
    }

    // -------- epilogue repack (reuse smem; last loop op was a barrier) -----
    // eKh/eKl: [hloc:4][p:64][k:20(16+4 pad)]; eV: [n:64][p-stride 68]
    __bf16* eKh = (__bf16*)smem;               // 5120 elems
    __bf16* eKl = eKh + 5120;                  // 5120
    __bf16* eV  = eKl + 5120;                  // 64*68 = 4352

    const int rbase = (lane >> 4) * 4;
#pragma unroll
    for (int mt = 0; mt < 2; ++mt)
#pragma unroll
        for (int nt = 0; nt < 2; ++nt) {
            const int hloc = (w & 1) * 2 + nt;
            const int nl = wn + nt * 16 + ln;
#pragma unroll
            for (int r = 0; r < 4; ++r) {
                const int m = wm + mt * 16 + rbase + r;
                const float vk = ak[mt][nt][r];
                const __bf16 hk = (__bf16)vk;
                eKh[(hloc * 64 + m) * 20 + ln] = hk;
                eKl[(hloc * 64 + m) * 20 + ln] = (__bf16)(vk - (float)hk);
                eV[nl * 68 + m] = (__bf16)av[mt][nt][r];
            }
        }
    __syncthreads();

    const int b = m0 >> 9;
    const int pbase = m0 & (PP - 1);
    {   // K stores: thread = (hloc, p); 32B contiguous per thread
        const int hl = tid >> 6, p = tid & 63;
        const int hg = (n0 >> 4) + hl;
        const size_t dst = (((size_t)b * HH + hg) * PP + pbase + p) * KD;
        const int base = (hl * 64 + p) * 20;
        uint2 a0 = *(const uint2*)&eKh[base + 0];
        uint2 a1 = *(const uint2*)&eKh[base + 4];
        uint2 a2 = *(const uint2*)&eKh[base + 8];
        uint2 a3 = *(const uint2*)&eKh[base + 12];
        *(uint4*)(Khi + dst)     = make_uint4(a0.x, a0.y, a1.x, a1.y);
        *(uint4*)(Khi + dst + 8) = make_uint4(a2.x, a2.y, a3.x, a3.y);
        uint2 c0 = *(const uint2*)&eKl[base + 0];
        uint2 c1 = *(const uint2*)&eKl[base + 4];
        uint2 c2 = *(const uint2*)&eKl[base + 8];
        uint2 c3 = *(const uint2*)&eKl[base + 12];
        *(uint4*)(Klo + dst)     = make_uint4(c0.x, c0.y, c1.x, c1.y);
        *(uint4*)(Klo + dst + 8) = make_uint4(c2.x, c2.y, c3.x, c3.y);
    }
    {   // V stores: thread = (n, quarter); 32B contiguous per thread
        const int n = tid >> 2, qq = tid & 3;
        const int ng = n0 + n, hg = ng >> 4, kk = ng & 15;
        const int base = n * 68 + qq * 16;
        uint2 v0 = *(const uint2*)&eV[base + 0];
        uint2 v1 = *(const uint2*)&eV[base + 4];
        uint2 v2 = *(const uint2*)&eV[base + 8];
        uint2 v3 = *(const uint2*)&eV[base + 12];
        const size_t dst = ((((size_t)b * HH + hg) * KD + kk) * PP) + pbase + qq * 16;
        *(uint4*)(Vt + dst)     = make_uint4(v0.x, v0.y, v1.x, v1.y);
        *(uint4*)(Vt + dst + 8) = make_uint4(v2.x, v2.y, v3.x, v3.y);
    }
}

// ---------------------------------------------------------------------------
// LDS-staged Q projection body (K=512 virtual concat A) + rank-1 ct epilogue.
// ---------------------------------------------------------------------------
__device__ inline void qproj_body(int bx, int tid, unsigned char* smem,
                                  const float* __restrict__ in1,
                                  const float* __restrict__ in2,
                                  const float* __restrict__ ct,
                                  const __bf16* __restrict__ Bh,
                                  const __bf16* __restrict__ Bl,
                                  const float* __restrict__ WqFull,
                                  __bf16* __restrict__ Qhi,
                                  __bf16* __restrict__ Qlo)
{
    __bf16* sAh = (__bf16*)smem;
    __bf16* sAl = sAh + 64 * SA_STRIDE;
    __bf16* sB  = sAl + 64 * SA_STRIDE;        // [2][64][SA_STRIDE]

    const int lane = tid & 63;
    const int w = __builtin_amdgcn_readfirstlane(tid >> 6);
    const int m0 = (bx >> 2) * 64;
    const int n0 = (bx & 3) * 64;
    const int wm = (w >> 1) * 32, wn = (w & 1) * 32;
    const int ln = lane & 15, kq = (lane >> 4) * 8;
    const int ar = tid >> 2, ac = (tid & 3) * 8;
    const int b = m0 >> 9;
    const float* WqLast = WqFull + (size_t)512 * HK;

    f32x4 acc[2][2];
#pragma unroll
    for (int i = 0; i < 2; ++i)
#pragma unroll
        for (int j = 0; j < 2; ++j) acc[i][j] = (f32x4){0.f, 0.f, 0.f, 0.f};

    for (int k0 = 0; k0 < 512; k0 += 32) {
        {
            const float* ap = (k0 < 256)
                ? in1 + (size_t)b * EE + k0 + ac
                : in2 + (size_t)(m0 + ar) * EE + (k0 - 256) + ac;
            bf16x8 h8, l8;
            cvt_split8(ap, h8, l8);
            *(bf16x8*)&sAh[ar * SA_STRIDE + ac] = h8;
            *(bf16x8*)&sAl[ar * SA_STRIDE + ac] = l8;
        }
        {   // B: 2 matrices; waves 0-1 -> hi, 2-3 -> lo; 2 lanes per row
            const int mat = w >> 1;
            const int row = (w & 1) * 32 + (lane >> 1);
            const int half = (lane & 1) * 16;
            const __bf16* src = (mat ? Bl : Bh) + ((size_t)(n0 + row) << 9) + k0 + half;
            __bf16* dst = sB + (mat * 64 + row) * SA_STRIDE + half;
            *(bf16x8*)&dst[0] = *(const bf16x8*)&src[0];
            *(bf16x8*)&dst[8] = *(const bf16x8*)&src[8];
        }
        __syncthreads();

        bf16x8 ah[2], al[2];
#pragma unroll
        for (int mt = 0; mt < 2; ++mt) {
            ah[mt] = *(const bf16x8*)&sAh[(wm + mt * 16 + ln) * SA_STRIDE + kq];
            al[mt] = *(const bf16x8*)&sAl[(wm + mt * 16 + ln) * SA_STRIDE + kq];
        }
#pragma unroll
        for (int nt = 0; nt < 2; ++nt) {
            const int rowb = wn + nt * 16 + ln;
            bf16x8 bh8 = *(const bf16x8*)&sB[(0 * 64 + rowb) * SA_STRIDE + kq];
            bf16x8 bl8 = *(const bf16x8*)&sB[(1 * 64 + rowb) * SA_STRIDE + kq];
#pragma unroll
            for (int mt = 0; mt < 2; ++mt) {
                acc[mt][nt] = __builtin_amdgcn_mfma_f32_16x16x32_bf16(ah[mt], bh8, acc[mt][nt], 0, 0, 0);
                acc[mt][nt] = __builtin_amdgcn_mfma_f32_16x16x32_bf16(al[mt], bh8, acc[mt][nt], 0, 0, 0);
                acc[mt][nt] = __builtin_amdgcn_mfma_f32_16x16x32_bf16(ah[mt], bl8, acc[mt][nt], 0, 0, 0);
            }
        }
        __syncthreads();
    }

    // epilogue: + ct[m]*WqLast[n], split, repack (same layout as K)
    __bf16* eQh = (__bf16*)smem;
    __bf16* eQl = eQh + 5120;

    const int rbase = (lane >> 4) * 4;
#pragma unroll
    for (int mt = 0; mt < 2; ++mt)
#pragma unroll
        for (int nt = 0; nt < 2; ++nt) {
            const int hloc = (w & 1) * 2 + nt;
            const int ng = n0 + wn + nt * 16 + ln;
            const float wq = WqLast[ng];
#pragma unroll
            for (int r = 0; r < 4; ++r) {
                const int m = wm + mt * 16 + rbase + r;
                const float v = acc[mt][nt][r] + ct[m0 + m] * wq;
                const __bf16 h = (__bf16)v;
                eQh[(hloc * 64 + m) * 20 + ln] = h;
                eQl[(hloc * 64 + m) * 20 + ln] = (__bf16)(v - (float)h);
            }
        }
    __syncthreads();

    {
        const int hl = tid >> 6, p = tid & 63;
        const int hg = (n0 >> 4) + hl;
        const int g = (m0 & (GG - 1)) + p;
        const size_t dst = (((size_t)b * HH + hg) * GG + g) * KD;
        const int base = (hl * 64 + p) * 20;
        uint2 a0 = *(const uint2*)&eQh[base + 0];
        uint2 a1 = *(const uint2*)&eQh[base + 4];
        uint2 a2 = *(const uint2*)&eQh[base + 8];
        uint2 a3 = *(const uint2*)&eQh[base + 12];
        *(uint4*)(Qhi + dst)     = make_uint4(a0.x, a0.y, a1.x, a1.y);
        *(uint4*)(Qhi + dst + 8) = make_uint4(a2.x, a2.y, a3.x, a3.y);
        uint2 c0 = *(const uint2*)&eQl[base + 0];
        uint2 c1 = *(const uint2*)&eQl[base + 4];
        uint2 c2 = *(const uint2*)&eQl[base + 8];
        uint2 c3 = *(const uint2*)&eQl[base + 12];
        *(uint4*)(Qlo + dst)     = make_uint4(c0.x, c0.y, c1.x, c1.y);
        *(uint4*)(Qlo + dst + 8) = make_uint4(c2.x, c2.y, c3.x, c3.y);
    }
}

// ---------------------------------------------------------------------------
// Fused K/V + Q projections: 1024 blocks.
// ---------------------------------------------------------------------------
__global__ __launch_bounds__(256, 2) void fused_proj(const float* __restrict__ enc,
                                                     const __bf16* __restrict__ Bkh,
                                                     const __bf16* __restrict__ Bkl,
                                                     const __bf16* __restrict__ Bvh,
                                                     const __bf16* __restrict__ Bvl,
                                                     __bf16* __restrict__ Khi,
                                                     __bf16* __restrict__ Klo,
                                                     __bf16* __restrict__ Vt,
                                                     const float* __restrict__ in1,
                                                     const float* __restrict__ in2,
                                                     const float* __restrict__ ct,
                                                     const __bf16* __restrict__ Bqh,
                                                     const __bf16* __restrict__ Bql,
                                                     const float* __restrict__ WqFull,
                                                     __bf16* __restrict__ Qhi,
                                                     __bf16* __restrict__ Qlo)
{
    __shared__ __align__(16) unsigned char smem[SMEM_BYTES];
    const int id = blockIdx.x;
    if (id < 512)
        kvproj_body(id, threadIdx.x, smem, enc, Bkh, Bkl, Bvh, Bvl, Khi, Klo, Vt);
    else
        qproj_body(id - 512, threadIdx.x, smem, in1, in2, ct, Bqh, Bql, WqFull, Qhi, Qlo);
}

// ---------------------------------------------------------------------------
// attn_v8 (verified round 8): one wave per (b, h, 32 g); 32x32x16 QK,
// sum-only flash, per-wave LDS P staging, 16x16x32 PV; bf16 hi/lo output.
// ---------------------------------------------------------------------------
__global__ __launch_bounds__(256, 4) void attn_v8(const __bf16* __restrict__ Qhi,
                                                  const __bf16* __restrict__ Qlo,
                                                  const __bf16* __restrict__ Khi,
                                                  const __bf16* __restrict__ Klo,
                                                  const __bf16* __restrict__ Vt,
                                                  const float* __restrict__ mask,
                                                  __bf16* __restrict__ Ath,
                                                  __bf16* __restrict__ Atl)
{
    __shared__ __align__(16) __bf16 sP[4][32][40];
    __shared__ float srs[4][32];

    const int t = threadIdx.x;
    const int lane = t & 63;
    const int w = __builtin_amdgcn_readfirstlane(t >> 6);
    const int g0 = blockIdx.x * 32;
    const int h = blockIdx.y * 4 + w;
    const int b = blockIdx.z;
    const int ln32 = lane & 31;
    const int half = lane >> 5;
    const int ln16 = lane & 15;
    const int quad = (lane >> 4) & 3;

    const size_t qbase = (((size_t)b * HH + h) * GG + g0) * KD;
    const size_t kbase = ((size_t)b * HH + h) * PP * KD;
    const size_t vbase = ((size_t)b * HH + h) * KD * PP;
    const float* mbase = mask + ((size_t)(b * GG + g0)) * PP;

    bf16x8 qah = *(const bf16x8*)(Qhi + qbase + (size_t)ln32 * KD + half * 8);
    bf16x8 qal = *(const bf16x8*)(Qlo + qbase + (size_t)ln32 * KD + half * 8);

    float rs[16];
#pragma unroll
    for (int r = 0; r < 16; ++r) rs[r] = 0.f;
    f32x4 o0 = (f32x4){0.f, 0.f, 0.f, 0.f};
    f32x4 o1 = (f32x4){0.f, 0.f, 0.f, 0.f};

#pragma unroll 2
    for (int pc = 0; pc < 16; ++pc) {
        const int pb = pc * 32;
        const size_t ko = kbase + (size_t)(pb + ln32) * KD + half * 8;
        bf16x8 kh = *(const bf16x8*)(Khi + ko);
        bf16x8 kl = *(const bf16x8*)(Klo + ko);

        f32x16 s = (f32x16){0.f, 0.f, 0.f, 0.f, 0.f, 0.f, 0.f, 0.f,
                            0.f, 0.f, 0.f, 0.f, 0.f, 0.f, 0.f, 0.f};
        s = __builtin_amdgcn_mfma_f32_32x32x16_bf16(qah, kh, s, 0, 0, 0);
        s = __builtin_amdgcn_mfma_f32_32x32x16_bf16(qal, kh, s, 0, 0, 0);
        s = __builtin_amdgcn_mfma_f32_32x32x16_bf16(qah, kl, s, 0, 0, 0);

#pragma unroll
        for (int r = 0; r < 16; ++r) {
            const int row = (r & 3) + 8 * (r >> 2) + 4 * half;
            const float m = mbase[(size_t)row * PP + pb + ln32];
            const float e = __expf(s[r] * 0.25f + m);
            rs[r] += e;
            sP[w][row][ln32] = (__bf16)e;
        }

        bf16x8 vb = *(const bf16x8*)(Vt + vbase + (size_t)ln16 * PP + pb + quad * 8);
        bf16x8 p0 = *(const bf16x8*)&sP[w][ln16][quad * 8];
        bf16x8 p1 = *(const bf16x8*)&sP[w][16 + ln16][quad * 8];
        o0 = __builtin_amdgcn_mfma_f32_16x16x32_bf16(p0, vb, o0, 0, 0, 0);
        o1 = __builtin_amdgcn_mfma_f32_16x16x32_bf16(p1, vb, o1, 0, 0, 0);
    }

#pragma unroll
    for (int r = 0; r < 16; ++r) {
#pragma unroll
        for (int mm = 1; mm < 32; mm <<= 1) rs[r] += __shfl_xor(rs[r], mm);
    }
    if (ln32 == 0) {
#pragma unroll
        for (int r = 0; r < 16; ++r)
            srs[w][(r & 3) + 8 * (r >> 2) + 4 * half] = rs[r];
    }

#pragma unroll
    for (int t2 = 0; t2 < 2; ++t2) {
        const f32x4 oc = t2 ? o1 : o0;
#pragma unroll
        for (int r = 0; r < 4; ++r) {
            const int grow = t2 * 16 + quad * 4 + r;
            const float v = oc[r] / srs[w][grow];
            const __bf16 hv = (__bf16)v;
            const size_t oo = ((size_t)(b * GG + g0 + grow)) * HK + h * KD + ln16;
            Ath[oo] = hv;
            Atl[oo] = (__bf16)(v - (float)hv);
        }
    }
}

// ---------------------------------------------------------------------------
// Fused post-attention: outproj (512 blocks) + enc prep_split (2048 blocks).
// ---------------------------------------------------------------------------
__device__ inline void outproj_body(int bx, int tid,
                                    const __bf16* __restrict__ Ah,
                                    const __bf16* __restrict__ Al,
                                    const __bf16* __restrict__ Bh,
                                    const __bf16* __restrict__ Bl,
                                    const float* __restrict__ bias,
                                    __bf16* __restrict__ Ch,
                                    __bf16* __restrict__ Cl)
{
    const int lane = tid & 63, w = tid >> 6;
    const int m0 = (bx >> 2) * 64 + (w >> 1) * 32;
    const int n0 = (bx & 3) * 64 + (w & 1) * 32;
    const int ln = lane & 15, kc = (lane >> 4) * 8;

    f32x4 acc[2][2];
#pragma unroll
    for (int i = 0; i < 2; ++i)
#pragma unroll
        for (int j = 0; j < 2; ++j) acc[i][j] = (f32x4){0.f, 0.f, 0.f, 0.f};

    for (int k0 = 0; k0 < EE; k0 += 32) {
        bf16x8 ah[2], al[2], bh[2], bl[2];
#pragma unroll
        for (int mt = 0; mt < 2; ++mt) {
            const size_t o = (size_t)(m0 + mt * 16 + ln) * EE + k0 + kc;
            ah[mt] = *(const bf16x8*)(Ah + o);
            al[mt] = *(const bf16x8*)(Al + o);
        }
#pragma unroll
        for (int nt = 0; nt < 2; ++nt) {
            const size_t o = (size_t)(n0 + nt * 16 + ln) * EE + k0 + kc;
            bh[nt] = *(const bf16x8*)(Bh + o);
            bl[nt] = *(const bf16x8*)(Bl + o);
        }
#pragma unroll
        for (int mt = 0; mt < 2; ++mt)
#pragma unroll
            for (int nt = 0; nt < 2; ++nt) {
                acc[mt][nt] = __builtin_amdgcn_mfma_f32_16x16x32_bf16(ah[mt], bh[nt], acc[mt][nt], 0, 0, 0);
                acc[mt][nt] = __builtin_amdgcn_mfma_f32_16x16x32_bf16(al[mt], bh[nt], acc[mt][nt], 0, 0, 0);
                acc[mt][nt] = __builtin_amdgcn_mfma_f32_16x16x32_bf16(ah[mt], bl[nt], acc[mt][nt], 0, 0, 0);
            }
    }

    const int rbase = (lane >> 4) * 4;
#pragma unroll
    for (int mt = 0; mt < 2; ++mt)
#pragma unroll
        for (int nt = 0; nt < 2; ++nt)
#pragma unroll
            for (int r = 0; r < 4; ++r) {
                const int m = m0 + rbase + r + mt * 16;
                const int n = n0 + nt * 16 + ln;
                const float v = acc[mt][nt][r] + bias[n];
                const __bf16 h = (__bf16)v;
                Ch[(size_t)m * HK + n] = h;
                Cl[(size_t)m * HK + n] = (__bf16)(v - (float)h);
            }
}

__global__ __launch_bounds__(256) void fused_post(const __bf16* __restrict__ Ah,
                                                  const __bf16* __restrict__ Al,
                                                  const __bf16* __restrict__ Bh,
                                                  const __bf16* __restrict__ Bl,
                                                  const float* __restrict__ bias,
                                                  __bf16* __restrict__ Ch,
                                                  __bf16* __restrict__ Cl,
                                                  const float* __restrict__ enc,
                                                  __bf16* __restrict__ enc_h,
                                                  __bf16* __restrict__ enc_l)
{
    const int id = blockIdx.x;
    if (id < 512) {
        outproj_body(id, threadIdx.x, Ah, Al, Bh, Bl, bias, Ch, Cl);
    } else {
        const int i = ((id - 512) * 256 + threadIdx.x) * 4;
        float4 v = *(const float4*)(enc + i);
        bf16x4 h, l;
        h[0] = (__bf16)v.x; l[0] = (__bf16)(v.x - (float)h[0]);
        h[1] = (__bf16)v.y; l[1] = (__bf16)(v.y - (float)h[1]);
        h[2] = (__bf16)v.z; l[2] = (__bf16)(v.z - (float)h[2]);
        h[3] = (__bf16)v.w; l[3] = (__bf16)(v.w - (float)h[3]);
        *(bf16x4*)(enc_h + i) = h;
        *(bf16x4*)(enc_l + i) = l;
    }
}

// ---------------------------------------------------------------------------
// Pointer head (round-6 verified form): pre-split enc, 4 waves x 128 p.
// ---------------------------------------------------------------------------
__global__ __launch_bounds__(256) void pointer_mfma(const __bf16* __restrict__ mh_hi,
                                                    const __bf16* __restrict__ mh_lo,
                                                    const __bf16* __restrict__ enc_hi,
                                                    const __bf16* __restrict__ enc_lo,
                                                    const float* __restrict__ mask,
                                                    float* __restrict__ out)
{
    __shared__ float sS[16][516];
    const int t = threadIdx.x;
    const int b = blockIdx.y, g0 = blockIdx.x * 16;
    const int lane = t & 63, w = t >> 6;
    const int lm = lane & 15;
    const int kc = (lane >> 4) * 8;

    const size_t arow = ((size_t)(b * GG + g0 + lm)) * EE + kc;
    const size_t brow = ((size_t)(b * PP + w * 128 + lm)) * EE + kc;

    f32x4 acc[8];
#pragma unroll
    for (int pt = 0; pt < 8; ++pt) acc[pt] = (f32x4){0.f, 0.f, 0.f, 0.f};

    for (int k0 = 0; k0 < EE; k0 += 32) {
        bf16x8 ah = *(const bf16x8*)(mh_hi + arow + k0);
        bf16x8 al = *(const bf16x8*)(mh_lo + arow + k0);
#pragma unroll
        for (int pt = 0; pt < 8; ++pt) {
            const size_t bo = brow + (size_t)pt * 16 * EE + k0;
            bf16x8 bh = *(const bf16x8*)(enc_hi + bo);
            bf16x8 bl = *(const bf16x8*)(enc_lo + bo);
            acc[pt] = __builtin_amdgcn_mfma_f32_16x16x32_bf16(ah, bh, acc[pt], 0, 0, 0);
            acc[pt] = __builtin_amdgcn_mfma_f32_16x16x32_bf16(al, bh, acc[pt], 0, 0, 0);
            acc[pt] = __builtin_amdgcn_mfma_f32_16x16x32_bf16(ah, bl, acc[pt], 0, 0, 0);
        }
    }

    const int rbase = (lane >> 4) * 4;
#pragma unroll
    for (int pt = 0; pt < 8; ++pt) {
        const int p = w * 128 + pt * 16 + lm;
#pragma unroll
        for (int r = 0; r < 4; ++r)
            sS[rbase + r][p] = acc[pt][r] * 0.0625f;
    }
    __syncthreads();

    const int g = t >> 4, j = t & 15;
    const float* mrow = mask + (size_t)(b * GG + g0 + g) * PP;
    float mx = -1e30f;
#pragma unroll 4
    for (int ii = 0; ii < 32; ++ii) {
        const int p = j + (ii << 4);
        const float s = 10.f * tanhf(sS[g][p]) + mrow[p];
        sS[g][p] = s;
        mx = fmaxf(mx, s);
    }
#pragma unroll
    for (int mbit = 1; mbit < 16; mbit <<= 1) mx = fmaxf(mx, __shfl_xor(mx, mbit));
    float sum = 0.f;
#pragma unroll 4
    for (int ii = 0; ii < 32; ++ii) {
        const int p = j + (ii << 4);
        const float e = __expf(sS[g][p] - mx);
        sS[g][p] = e;
        sum += e;
    }
#pragma unroll
    for (int mbit = 1; mbit < 16; mbit <<= 1) sum += __shfl_xor(sum, mbit);
    const float inv = 1.f / sum;
    float* orow = out + (size_t)(b * GG + g0 + g) * PP;
#pragma unroll 4
    for (int ii = 0; ii < 32; ++ii) {
        const int p = j + (ii << 4);
        orow[p] = sS[g][p] * inv;
    }
}

// ---------------------------------------------------------------------------
extern "C" void kernel_launch(void* const* d_in, const int* in_sizes, int n_in,
                              void* d_out, int out_size, void* d_ws, size_t ws_size,
                              hipStream_t stream)
{
    const float* in1  = (const float*)d_in[0];
    const float* in2  = (const float*)d_in[1];
    const float* ct   = (const float*)d_in[2];
    const float* mask = (const float*)d_in[3];
    const float* enc  = (const float*)d_in[4];
    const float* Wq   = (const float*)d_in[5];
    const float* Wk   = (const float*)d_in[6];
    const float* Wv   = (const float*)d_in[7];
    const float* Wcw  = (const float*)d_in[8];
    const float* Wcb  = (const float*)d_in[9];
    float* out = (float*)d_out;
    float* ws  = (float*)d_ws;

    const size_t SEG = (size_t)BB * GG * HK;  // 2M elements; 32 MB total ws
    __bf16* Khi = (__bf16*)ws;
    __bf16* Klo = Khi + SEG;
    __bf16* Vt  = (__bf16*)(ws + SEG);
    __bf16* Ath = Vt + SEG;
    __bf16* Qhi = (__bf16*)(ws + 2 * SEG);
    __bf16* Qlo = Qhi + SEG;
    __bf16* wkt_h = (__bf16*)(ws + 3 * SEG);
    __bf16* wkt_l = wkt_h + 65536;
    __bf16* wvt_h = wkt_l + 65536;
    __bf16* wvt_l = wvt_h + 65536;
    __bf16* wqt_h = wvt_l + 65536;
    __bf16* wqt_l = wqt_h + 131072;
    __bf16* wct_h = wqt_l + 131072;
    __bf16* wct_l = wct_h + 65536;
    __bf16* Atl   = (__bf16*)(ws + 3 * SEG) + 1048576;
    __bf16* mh_h  = (__bf16*)ws;
    __bf16* mh_l  = mh_h + SEG;
    __bf16* enc_h = (__bf16*)(ws + 2 * SEG);
    __bf16* enc_l = enc_h + SEG;

    const dim3 blk(256);

    weight_prep<<<dim3(1280), blk, 0, stream>>>(Wk, Wv, Wq, Wcw,
                                                wkt_h, wkt_l, wvt_h, wvt_l,
                                                wqt_h, wqt_l, wct_h, wct_l);

    fused_proj<<<dim3(1024), blk, 0, stream>>>(enc, wkt_h, wkt_l, wvt_h, wvt_l,
                                               Khi, Klo, Vt,
                                               in1, in2, ct, wqt_h, wqt_l, Wq,
                                               Qhi, Qlo);

    attn_v8<<<dim3(GG / 32, HH / 4, BB), blk, 0, stream>>>(Qhi, Qlo, Khi, Klo, Vt, mask, Ath, Atl);

    fused_post<<<dim3(2560), blk, 0, stream>>>(Ath, Atl, wct_h, wct_l, Wcb,
                                               mh_h, mh_l, enc, enc_h, enc_l);

    pointer_mfma<<<dim3(GG / 16, BB), blk, 0, stream>>>(mh_h, mh_l, enc_h, enc_l, mask, out);
}

// Round 11
// 216.893 us; speedup vs baseline: 1.4737x; 1.0188x over previous
//
#include <hip/hip_runtime.h>
#include <math.h>

#define BB 16
#define GG 512
#define PP 512
#define EE 256
#define HH 16
#define KD 16
#define HK 256

typedef __bf16 bf16x8 __attribute__((ext_vector_type(8)));
typedef __bf16 bf16x4 __attribute__((ext_vector_type(4)));
typedef float f32x4 __attribute__((ext_vector_type(4)));
typedef float f32x16 __attribute__((ext_vector_type(16)));

// LDS geometry for fused_proj (bytes): compute phase 30720, epilogue 29184.
#define SA_STRIDE 40           // 32 cols + 8 pad (80B rows: 16B-aligned, <=4-way banks)
#define SMEM_BYTES 30720

__device__ inline void cvt_split8(const float* __restrict__ p, bf16x8& h, bf16x8& l)
{
    float4 f0 = *(const float4*)p;
    float4 f1 = *(const float4*)(p + 4);
    float v[8] = {f0.x, f0.y, f0.z, f0.w, f1.x, f1.y, f1.z, f1.w};
#pragma unroll
    for (int j = 0; j < 8; ++j) {
        __bf16 hh = (__bf16)v[j];
        h[j] = hh;
        l[j] = (__bf16)(v[j] - (float)hh);
    }
}

// ---------------------------------------------------------------------------
// All four weight transpose+splits in one launch.
// ---------------------------------------------------------------------------
__global__ __launch_bounds__(256) void weight_prep(const float* __restrict__ Wk,
                                                   const float* __restrict__ Wv,
                                                   const float* __restrict__ Wq,
                                                   const float* __restrict__ Wc,
                                                   __bf16* __restrict__ wkt_h, __bf16* __restrict__ wkt_l,
                                                   __bf16* __restrict__ wvt_h, __bf16* __restrict__ wvt_l,
                                                   __bf16* __restrict__ wqt_h, __bf16* __restrict__ wqt_l,
                                                   __bf16* __restrict__ wct_h, __bf16* __restrict__ wct_l)
{
    int id = blockIdx.x * 256 + threadIdx.x;
    const float* W;
    __bf16 *th, *tl;
    int kbits;
    if (id < 65536)       { W = Wk; th = wkt_h; tl = wkt_l; kbits = 8; }
    else if (id < 131072) { id -= 65536;  W = Wv; th = wvt_h; tl = wvt_l; kbits = 8; }
    else if (id < 262144) { id -= 131072; W = Wq; th = wqt_h; tl = wqt_l; kbits = 9; }
    else                  { id -= 262144; W = Wc; th = wct_h; tl = wct_l; kbits = 8; }
    const int Kd = 1 << kbits;
    const int k = id & (Kd - 1);
    const int n = id >> kbits;
    const float v = W[(size_t)k * HK + n];
    const __bf16 h = (__bf16)v;
    th[((size_t)n << kbits) + k] = h;
    tl[((size_t)n << kbits) + k] = (__bf16)(v - (float)h);
}

// ---------------------------------------------------------------------------
// LDS-staged fused K/V projection body (verified round 10).
// ---------------------------------------------------------------------------
__device__ inline void kvproj_body(int bx, int tid, unsigned char* smem,
                                   const float* __restrict__ A,
                                   const __bf16* __restrict__ Bkh,
                                   const __bf16* __restrict__ Bkl,
                                   const __bf16* __restrict__ Bvh,
                                   const __bf16* __restrict__ Bvl,
                                   __bf16* __restrict__ Khi,
                                   __bf16* __restrict__ Klo,
                                   __bf16* __restrict__ Vt)
{
    __bf16* sAh = (__bf16*)smem;               // [64][SA_STRIDE]
    __bf16* sAl = sAh + 64 * SA_STRIDE;
    __bf16* sB  = sAl + 64 * SA_STRIDE;        // [4][64][SA_STRIDE]

    const int lane = tid & 63;
    const int w = __builtin_amdgcn_readfirstlane(tid >> 6);
    const int m0 = (bx >> 2) * 64;
    const int n0 = (bx & 3) * 64;
    const int wm = (w >> 1) * 32, wn = (w & 1) * 32;
    const int ln = lane & 15, kq = (lane >> 4) * 8;
    const int ar = tid >> 2, ac = (tid & 3) * 8;

    const __bf16* bsel = (w == 0) ? Bkh : (w == 1) ? Bkl : (w == 2) ? Bvh : Bvl;

    f32x4 ak[2][2], av[2][2];
#pragma unroll
    for (int i = 0; i < 2; ++i)
#pragma unroll
        for (int j = 0; j < 2; ++j) {
            ak[i][j] = (f32x4){0.f, 0.f, 0.f, 0.f};
            av[i][j] = (f32x4){0.f, 0.f, 0.f, 0.f};
        }

    for (int k0 = 0; k0 < EE; k0 += 32) {
        {
            bf16x8 h8, l8;
            cvt_split8(A + (size_t)(m0 + ar) * EE + k0 + ac, h8, l8);
            *(bf16x8*)&sAh[ar * SA_STRIDE + ac] = h8;
            *(bf16x8*)&sAl[ar * SA_STRIDE + ac] = l8;
        }
        {
            const __bf16* src = bsel + (size_t)(n0 + lane) * EE + k0;
            __bf16* dst = sB + (w * 64 + lane) * SA_STRIDE;
            *(bf16x8*)&dst[0]  = *(const bf16x8*)&src[0];
            *(bf16x8*)&dst[8]  = *(const bf16x8*)&src[8];
            *(bf16x8*)&dst[16] = *(const bf16x8*)&src[16];
            *(bf16x8*)&dst[24] = *(const bf16x8*)&src[24];
        }
        __syncthreads();

        bf16x8 ah[2], al[2];
#pragma unroll
        for (int mt = 0; mt < 2; ++mt) {
            ah[mt] = *(const bf16x8*)&sAh[(wm + mt * 16 + ln) * SA_STRIDE + kq];
            al[mt] = *(const bf16x8*)&sAl[(wm + mt * 16 + ln) * SA_STRIDE + kq];
        }
#pragma unroll
        for (int nt = 0; nt < 2; ++nt) {
            const int rowb = wn + nt * 16 + ln;
            bf16x8 bkh8 = *(const bf16x8*)&sB[(0 * 64 + rowb) * SA_STRIDE + kq];
            bf16x8 bkl8 = *(const bf16x8*)&sB[(1 * 64 + rowb) * SA_STRIDE + kq];
            bf16x8 bvh8 = *(const bf16x8*)&sB[(2 * 64 + rowb) * SA_STRIDE + kq];
            bf16x8 bvl8 = *(const bf16x8*)&sB[(3 * 64 + rowb) * SA_STRIDE + kq];
#pragma unroll
            for (int mt = 0; mt < 2; ++mt) {
                ak[mt][nt] = __builtin_amdgcn_mfma_f32_16x16x32_bf16(ah[mt], bkh8, ak[mt][nt], 0, 0, 0);
                ak[mt][nt] = __builtin_amdgcn_mfma_f32_16x16x32_bf16(al[mt], bkh8, ak[mt][nt], 0, 0, 0);
                ak[mt][nt] = __builtin_amdgcn_mfma_f32_16x16x32_bf16(ah[mt], bkl8, ak[mt][nt], 0, 0, 0);
                av[mt][nt] = __builtin_amdgcn_mfma_f32_16x16x32_bf16(ah[mt], bvh8, av[mt][nt], 0, 0, 0);
                av[mt][nt] = __builtin_amdgcn_mfma_f32_16x16x32_bf16(al[mt], bvh8, av[mt][nt], 0, 0, 0);
                av[mt][nt] = __builtin_amdgcn_mfma_f32_16x16x32_bf16(ah[mt], bvl8, av[mt][nt], 0, 0, 0);
            }
        }
        __syncthreads();
    }

    __bf16* eKh = (__bf16*)smem;
    __bf16* eKl = eKh + 5120;
    __bf16* eV  = eKl + 5120;

    const int rbase = (lane >> 4) * 4;
#pragma unroll
    for (int mt = 0; mt < 2; ++mt)
#pragma unroll
        for (int nt = 0; nt < 2; ++nt) {
            const int hloc = (w & 1) * 2 + nt;
            const int nl = wn + nt * 16 + ln;
#pragma unroll
            for (int r = 0; r < 4; ++r) {
                const int m = wm + mt * 16 + rbase + r;
                const float vk = ak[mt][nt][r];
                const __bf16 hk = (__bf16)vk;
                eKh[(hloc * 64 + m) * 20 + ln] = hk;
                eKl[(hloc * 64 + m) * 20 + ln] = (__bf16)(vk - (float)hk);
                eV[nl * 68 + m] = (__bf16)av[mt][nt][r];
            }
        }
    __syncthreads();

    const int b = m0 >> 9;
    const int pbase = m0 & (PP - 1);
    {
        const int hl = tid >> 6, p = tid & 63;
        const int hg = (n0 >> 4) + hl;
        const size_t dst = (((size_t)b * HH + hg) * PP + pbase + p) * KD;
        const int base = (hl * 64 + p) * 20;
        uint2 a0 = *(const uint2*)&eKh[base + 0];
        uint2 a1 = *(const uint2*)&eKh[base + 4];
        uint2 a2 = *(const uint2*)&eKh[base + 8];
        uint2 a3 = *(const uint2*)&eKh[base + 12];
        *(uint4*)(Khi + dst)     = make_uint4(a0.x, a0.y, a1.x, a1.y);
        *(uint4*)(Khi + dst + 8) = make_uint4(a2.x, a2.y, a3.x, a3.y);
        uint2 c0 = *(const uint2*)&eKl[base + 0];
        uint2 c1 = *(const uint2*)&eKl[base + 4];
        uint2 c2 = *(const uint2*)&eKl[base + 8];
        uint2 c3 = *(const uint2*)&eKl[base + 12];
        *(uint4*)(Klo + dst)     = make_uint4(c0.x, c0.y, c1.x, c1.y);
        *(uint4*)(Klo + dst + 8) = make_uint4(c2.x, c2.y, c3.x, c3.y);
    }
    {
        const int n = tid >> 2, qq = tid & 3;
        const int ng = n0 + n, hg = ng >> 4, kk = ng & 15;
        const int base = n * 68 + qq * 16;
        uint2 v0 = *(const uint2*)&eV[base + 0];
        uint2 v1 = *(const uint2*)&eV[base + 4];
        uint2 v2 = *(const uint2*)&eV[base + 8];
        uint2 v3 = *(const uint2*)&eV[base + 12];
        const size_t dst = ((((size_t)b * HH + hg) * KD + kk) * PP) + pbase + qq * 16;
        *(uint4*)(Vt + dst)     = make_uint4(v0.x, v0.y, v1.x, v1.y);
        *(uint4*)(Vt + dst + 8) = make_uint4(v2.x, v2.y, v3.x, v3.y);
    }
}

// ---------------------------------------------------------------------------
// LDS-staged Q projection body (verified round 10).
// ---------------------------------------------------------------------------
__device__ inline void qproj_body(int bx, int tid, unsigned char* smem,
                                  const float* __restrict__ in1,
                                  const float* __restrict__ in2,
                                  const float* __restrict__ ct,
                                  const __bf16* __restrict__ Bh,
                                  const __bf16* __restrict__ Bl,
                                  const float* __restrict__ WqFull,
                                  __bf16* __restrict__ Qhi,
                                  __bf16* __restrict__ Qlo)
{
    __bf16* sAh = (__bf16*)smem;
    __bf16* sAl = sAh + 64 * SA_STRIDE;
    __bf16* sB  = sAl + 64 * SA_STRIDE;

    const int lane = tid & 63;
    const int w = __builtin_amdgcn_readfirstlane(tid >> 6);
    const int m0 = (bx >> 2) * 64;
    const int n0 = (bx & 3) * 64;
    const int wm = (w >> 1) * 32, wn = (w & 1) * 32;
    const int ln = lane & 15, kq = (lane >> 4) * 8;
    const int ar = tid >> 2, ac = (tid & 3) * 8;
    const int b = m0 >> 9;
    const float* WqLast = WqFull + (size_t)512 * HK;

    f32x4 acc[2][2];
#pragma unroll
    for (int i = 0; i < 2; ++i)
#pragma unroll
        for (int j = 0; j < 2; ++j) acc[i][j] = (f32x4){0.f, 0.f, 0.f, 0.f};

    for (int k0 = 0; k0 < 512; k0 += 32) {
        {
            const float* ap = (k0 < 256)
                ? in1 + (size_t)b * EE + k0 + ac
                : in2 + (size_t)(m0 + ar) * EE + (k0 - 256) + ac;
            bf16x8 h8, l8;
            cvt_split8(ap, h8, l8);
            *(bf16x8*)&sAh[ar * SA_STRIDE + ac] = h8;
            *(bf16x8*)&sAl[ar * SA_STRIDE + ac] = l8;
        }
        {
            const int mat = w >> 1;
            const int row = (w & 1) * 32 + (lane >> 1);
            const int half = (lane & 1) * 16;
            const __bf16* src = (mat ? Bl : Bh) + ((size_t)(n0 + row) << 9) + k0 + half;
            __bf16* dst = sB + (mat * 64 + row) * SA_STRIDE + half;
            *(bf16x8*)&dst[0] = *(const bf16x8*)&src[0];
            *(bf16x8*)&dst[8] = *(const bf16x8*)&src[8];
        }
        __syncthreads();

        bf16x8 ah[2], al[2];
#pragma unroll
        for (int mt = 0; mt < 2; ++mt) {
            ah[mt] = *(const bf16x8*)&sAh[(wm + mt * 16 + ln) * SA_STRIDE + kq];
            al[mt] = *(const bf16x8*)&sAl[(wm + mt * 16 + ln) * SA_STRIDE + kq];
        }
#pragma unroll
        for (int nt = 0; nt < 2; ++nt) {
            const int rowb = wn + nt * 16 + ln;
            bf16x8 bh8 = *(const bf16x8*)&sB[(0 * 64 + rowb) * SA_STRIDE + kq];
            bf16x8 bl8 = *(const bf16x8*)&sB[(1 * 64 + rowb) * SA_STRIDE + kq];
#pragma unroll
            for (int mt = 0; mt < 2; ++mt) {
                acc[mt][nt] = __builtin_amdgcn_mfma_f32_16x16x32_bf16(ah[mt], bh8, acc[mt][nt], 0, 0, 0);
                acc[mt][nt] = __builtin_amdgcn_mfma_f32_16x16x32_bf16(al[mt], bh8, acc[mt][nt], 0, 0, 0);
                acc[mt][nt] = __builtin_amdgcn_mfma_f32_16x16x32_bf16(ah[mt], bl8, acc[mt][nt], 0, 0, 0);
            }
        }
        __syncthreads();
    }

    __bf16* eQh = (__bf16*)smem;
    __bf16* eQl = eQh + 5120;

    const int rbase = (lane >> 4) * 4;
#pragma unroll
    for (int mt = 0; mt < 2; ++mt)
#pragma unroll
        for (int nt = 0; nt < 2; ++nt) {
            const int hloc = (w & 1) * 2 + nt;
            const int ng = n0 + wn + nt * 16 + ln;
            const float wq = WqLast[ng];
#pragma unroll
            for (int r = 0; r < 4; ++r) {
                const int m = wm + mt * 16 + rbase + r;
                const float v = acc[mt][nt][r] + ct[m0 + m] * wq;
                const __bf16 h = (__bf16)v;
                eQh[(hloc * 64 + m) * 20 + ln] = h;
                eQl[(hloc * 64 + m) * 20 + ln] = (__bf16)(v - (float)h);
            }
        }
    __syncthreads();

    {
        const int hl = tid >> 6, p = tid & 63;
        const int hg = (n0 >> 4) + hl;
        const int g = (m0 & (GG - 1)) + p;
        const size_t dst = (((size_t)b * HH + hg) * GG + g) * KD;
        const int base = (hl * 64 + p) * 20;
        uint2 a0 = *(const uint2*)&eQh[base + 0];
        uint2 a1 = *(const uint2*)&eQh[base + 4];
        uint2 a2 = *(const uint2*)&eQh[base + 8];
        uint2 a3 = *(const uint2*)&eQh[base + 12];
        *(uint4*)(Qhi + dst)     = make_uint4(a0.x, a0.y, a1.x, a1.y);
        *(uint4*)(Qhi + dst + 8) = make_uint4(a2.x, a2.y, a3.x, a3.y);
        uint2 c0 = *(const uint2*)&eQl[base + 0];
        uint2 c1 = *(const uint2*)&eQl[base + 4];
        uint2 c2 = *(const uint2*)&eQl[base + 8];
        uint2 c3 = *(const uint2*)&eQl[base + 12];
        *(uint4*)(Qlo + dst)     = make_uint4(c0.x, c0.y, c1.x, c1.y);
        *(uint4*)(Qlo + dst + 8) = make_uint4(c2.x, c2.y, c3.x, c3.y);
    }
}

// ---------------------------------------------------------------------------
// Fused K/V + Q projections: 1024 blocks.
// ---------------------------------------------------------------------------
__global__ __launch_bounds__(256, 2) void fused_proj(const float* __restrict__ enc,
                                                     const __bf16* __restrict__ Bkh,
                                                     const __bf16* __restrict__ Bkl,
                                                     const __bf16* __restrict__ Bvh,
                                                     const __bf16* __restrict__ Bvl,
                                                     __bf16* __restrict__ Khi,
                                                     __bf16* __restrict__ Klo,
                                                     __bf16* __restrict__ Vt,
                                                     const float* __restrict__ in1,
                                                     const float* __restrict__ in2,
                                                     const float* __restrict__ ct,
                                                     const __bf16* __restrict__ Bqh,
                                                     const __bf16* __restrict__ Bql,
                                                     const float* __restrict__ WqFull,
                                                     __bf16* __restrict__ Qhi,
                                                     __bf16* __restrict__ Qlo)
{
    __shared__ __align__(16) unsigned char smem[SMEM_BYTES];
    const int id = blockIdx.x;
    if (id < 512)
        kvproj_body(id, threadIdx.x, smem, enc, Bkh, Bkl, Bvh, Bvl, Khi, Klo, Vt);
    else
        qproj_body(id - 512, threadIdx.x, smem, in1, in2, ct, Bqh, Bql, WqFull, Qhi, Qlo);
}

// ---------------------------------------------------------------------------
// attn_v8 (verified round 8): one wave per (b, h, 32 g); 32x32x16 QK,
// sum-only flash, per-wave LDS P staging, 16x16x32 PV; bf16 hi/lo output.
// ---------------------------------------------------------------------------
__global__ __launch_bounds__(256, 4) void attn_v8(const __bf16* __restrict__ Qhi,
                                                  const __bf16* __restrict__ Qlo,
                                                  const __bf16* __restrict__ Khi,
                                                  const __bf16* __restrict__ Klo,
                                                  const __bf16* __restrict__ Vt,
                                                  const float* __restrict__ mask,
                                                  __bf16* __restrict__ Ath,
                                                  __bf16* __restrict__ Atl)
{
    __shared__ __align__(16) __bf16 sP[4][32][40];
    __shared__ float srs[4][32];

    const int t = threadIdx.x;
    const int lane = t & 63;
    const int w = __builtin_amdgcn_readfirstlane(t >> 6);
    const int g0 = blockIdx.x * 32;
    const int h = blockIdx.y * 4 + w;
    const int b = blockIdx.z;
    const int ln32 = lane & 31;
    const int half = lane >> 5;
    const int ln16 = lane & 15;
    const int quad = (lane >> 4) & 3;

    const size_t qbase = (((size_t)b * HH + h) * GG + g0) * KD;
    const size_t kbase = ((size_t)b * HH + h) * PP * KD;
    const size_t vbase = ((size_t)b * HH + h) * KD * PP;
    const float* mbase = mask + ((size_t)(b * GG + g0)) * PP;

    bf16x8 qah = *(const bf16x8*)(Qhi + qbase + (size_t)ln32 * KD + half * 8);
    bf16x8 qal = *(const bf16x8*)(Qlo + qbase + (size_t)ln32 * KD + half * 8);

    float rs[16];
#pragma unroll
    for (int r = 0; r < 16; ++r) rs[r] = 0.f;
    f32x4 o0 = (f32x4){0.f, 0.f, 0.f, 0.f};
    f32x4 o1 = (f32x4){0.f, 0.f, 0.f, 0.f};

#pragma unroll 2
    for (int pc = 0; pc < 16; ++pc) {
        const int pb = pc * 32;
        const size_t ko = kbase + (size_t)(pb + ln32) * KD + half * 8;
        bf16x8 kh = *(const bf16x8*)(Khi + ko);
        bf16x8 kl = *(const bf16x8*)(Klo + ko);

        f32x16 s = (f32x16){0.f, 0.f, 0.f, 0.f, 0.f, 0.f, 0.f, 0.f,
                            0.f, 0.f, 0.f, 0.f, 0.f, 0.f, 0.f, 0.f};
        s = __builtin_amdgcn_mfma_f32_32x32x16_bf16(qah, kh, s, 0, 0, 0);
        s = __builtin_amdgcn_mfma_f32_32x32x16_bf16(qal, kh, s, 0, 0, 0);
        s = __builtin_amdgcn_mfma_f32_32x32x16_bf16(qah, kl, s, 0, 0, 0);

#pragma unroll
        for (int r = 0; r < 16; ++r) {
            const int row = (r & 3) + 8 * (r >> 2) + 4 * half;
            const float m = mbase[(size_t)row * PP + pb + ln32];
            const float e = __expf(s[r] * 0.25f + m);
            rs[r] += e;
            sP[w][row][ln32] = (__bf16)e;
        }

        bf16x8 vb = *(const bf16x8*)(Vt + vbase + (size_t)ln16 * PP + pb + quad * 8);
        bf16x8 p0 = *(const bf16x8*)&sP[w][ln16][quad * 8];
        bf16x8 p1 = *(const bf16x8*)&sP[w][16 + ln16][quad * 8];
        o0 = __builtin_amdgcn_mfma_f32_16x16x32_bf16(p0, vb, o0, 0, 0, 0);
        o1 = __builtin_amdgcn_mfma_f32_16x16x32_bf16(p1, vb, o1, 0, 0, 0);
    }

#pragma unroll
    for (int r = 0; r < 16; ++r) {
#pragma unroll
        for (int mm = 1; mm < 32; mm <<= 1) rs[r] += __shfl_xor(rs[r], mm);
    }
    if (ln32 == 0) {
#pragma unroll
        for (int r = 0; r < 16; ++r)
            srs[w][(r & 3) + 8 * (r >> 2) + 4 * half] = rs[r];
    }

#pragma unroll
    for (int t2 = 0; t2 < 2; ++t2) {
        const f32x4 oc = t2 ? o1 : o0;
#pragma unroll
        for (int r = 0; r < 4; ++r) {
            const int grow = t2 * 16 + quad * 4 + r;
            const float v = oc[r] / srs[w][grow];
            const __bf16 hv = (__bf16)v;
            const size_t oo = ((size_t)(b * GG + g0 + grow)) * HK + h * KD + ln16;
            Ath[oo] = hv;
            Atl[oo] = (__bf16)(v - (float)hv);
        }
    }
}

// ---------------------------------------------------------------------------
// Fused post-attention: outproj (512 blocks) + enc prep_split (2048 blocks).
// ---------------------------------------------------------------------------
__device__ inline void outproj_body(int bx, int tid,
                                    const __bf16* __restrict__ Ah,
                                    const __bf16* __restrict__ Al,
                                    const __bf16* __restrict__ Bh,
                                    const __bf16* __restrict__ Bl,
                                    const float* __restrict__ bias,
                                    __bf16* __restrict__ Ch,
                                    __bf16* __restrict__ Cl)
{
    const int lane = tid & 63, w = tid >> 6;
    const int m0 = (bx >> 2) * 64 + (w >> 1) * 32;
    const int n0 = (bx & 3) * 64 + (w & 1) * 32;
    const int ln = lane & 15, kc = (lane >> 4) * 8;

    f32x4 acc[2][2];
#pragma unroll
    for (int i = 0; i < 2; ++i)
#pragma unroll
        for (int j = 0; j < 2; ++j) acc[i][j] = (f32x4){0.f, 0.f, 0.f, 0.f};

    for (int k0 = 0; k0 < EE; k0 += 32) {
        bf16x8 ah[2], al[2], bh[2], bl[2];
#pragma unroll
        for (int mt = 0; mt < 2; ++mt) {
            const size_t o = (size_t)(m0 + mt * 16 + ln) * EE + k0 + kc;
            ah[mt] = *(const bf16x8*)(Ah + o);
            al[mt] = *(const bf16x8*)(Al + o);
        }
#pragma unroll
        for (int nt = 0; nt < 2; ++nt) {
            const size_t o = (size_t)(n0 + nt * 16 + ln) * EE + k0 + kc;
            bh[nt] = *(const bf16x8*)(Bh + o);
            bl[nt] = *(const bf16x8*)(Bl + o);
        }
#pragma unroll
        for (int mt = 0; mt < 2; ++mt)
#pragma unroll
            for (int nt = 0; nt < 2; ++nt) {
                acc[mt][nt] = __builtin_amdgcn_mfma_f32_16x16x32_bf16(ah[mt], bh[nt], acc[mt][nt], 0, 0, 0);
                acc[mt][nt] = __builtin_amdgcn_mfma_f32_16x16x32_bf16(al[mt], bh[nt], acc[mt][nt], 0, 0, 0);
                acc[mt][nt] = __builtin_amdgcn_mfma_f32_16x16x32_bf16(ah[mt], bl[nt], acc[mt][nt], 0, 0, 0);
            }
    }

    const int rbase = (lane >> 4) * 4;
#pragma unroll
    for (int mt = 0; mt < 2; ++mt)
#pragma unroll
        for (int nt = 0; nt < 2; ++nt)
#pragma unroll
            for (int r = 0; r < 4; ++r) {
                const int m = m0 + rbase + r + mt * 16;
                const int n = n0 + nt * 16 + ln;
                const float v = acc[mt][nt][r] + bias[n];
                const __bf16 h = (__bf16)v;
                Ch[(size_t)m * HK + n] = h;
                Cl[(size_t)m * HK + n] = (__bf16)(v - (float)h);
            }
}

__global__ __launch_bounds__(256) void fused_post(const __bf16* __restrict__ Ah,
                                                  const __bf16* __restrict__ Al,
                                                  const __bf16* __restrict__ Bh,
                                                  const __bf16* __restrict__ Bl,
                                                  const float* __restrict__ bias,
                                                  __bf16* __restrict__ Ch,
                                                  __bf16* __restrict__ Cl,
                                                  const float* __restrict__ enc,
                                                  __bf16* __restrict__ enc_h,
                                                  __bf16* __restrict__ enc_l)
{
    const int id = blockIdx.x;
    if (id < 512) {
        outproj_body(id, threadIdx.x, Ah, Al, Bh, Bl, bias, Ch, Cl);
    } else {
        const int i = ((id - 512) * 256 + threadIdx.x) * 4;
        float4 v = *(const float4*)(enc + i);
        bf16x4 h, l;
        h[0] = (__bf16)v.x; l[0] = (__bf16)(v.x - (float)h[0]);
        h[1] = (__bf16)v.y; l[1] = (__bf16)(v.y - (float)h[1]);
        h[2] = (__bf16)v.z; l[2] = (__bf16)(v.z - (float)h[2]);
        h[3] = (__bf16)v.w; l[3] = (__bf16)(v.w - (float)h[3]);
        *(bf16x4*)(enc_h + i) = h;
        *(bf16x4*)(enc_l + i) = l;
    }
}

// ---------------------------------------------------------------------------
// Pointer head v2: 512 threads (8 waves x 64 p), register softmax.
// Scores are bounded by the 10*tanh clip -> exp without max-subtraction is
// fp32-safe (<= 512*e^10 ~ 1.1e7). tanh via one __expf with +-9 clamp.
// Row sums: 16-lane shuffle + tiny cross-wave LDS. No score LDS at all.
// ---------------------------------------------------------------------------
__global__ __launch_bounds__(512) void pointer_v2(const __bf16* __restrict__ mh_hi,
                                                  const __bf16* __restrict__ mh_lo,
                                                  const __bf16* __restrict__ enc_hi,
                                                  const __bf16* __restrict__ enc_lo,
                                                  const float* __restrict__ mask,
                                                  float* __restrict__ out)
{
    __shared__ float swsum[8][16];
    const int t = threadIdx.x;
    const int lane = t & 63;
    const int w = __builtin_amdgcn_readfirstlane(t >> 6);  // 0..7, 64 p each
    const int b = blockIdx.y, g0 = blockIdx.x * 16;
    const int lm = lane & 15;
    const int kc = (lane >> 4) * 8;
    const int quad = lane >> 4;
    const int rbase = quad * 4;

    const size_t arow = ((size_t)(b * GG + g0 + lm)) * EE + kc;
    const size_t brow = ((size_t)(b * PP + w * 64 + lm)) * EE + kc;

    f32x4 acc[4];
#pragma unroll
    for (int pt = 0; pt < 4; ++pt) acc[pt] = (f32x4){0.f, 0.f, 0.f, 0.f};

    for (int k0 = 0; k0 < EE; k0 += 32) {
        bf16x8 ah = *(const bf16x8*)(mh_hi + arow + k0);
        bf16x8 al = *(const bf16x8*)(mh_lo + arow + k0);
#pragma unroll
        for (int pt = 0; pt < 4; ++pt) {
            const size_t bo = brow + (size_t)pt * 16 * EE + k0;
            bf16x8 bh = *(const bf16x8*)(enc_hi + bo);
            bf16x8 bl = *(const bf16x8*)(enc_lo + bo);
            acc[pt] = __builtin_amdgcn_mfma_f32_16x16x32_bf16(ah, bh, acc[pt], 0, 0, 0);
            acc[pt] = __builtin_amdgcn_mfma_f32_16x16x32_bf16(al, bh, acc[pt], 0, 0, 0);
            acc[pt] = __builtin_amdgcn_mfma_f32_16x16x32_bf16(ah, bl, acc[pt], 0, 0, 0);
        }
    }

    // clip + mask + exp, all in registers. acc[pt][r] = S[g0+rbase+r][w*64+pt*16+lm]
    float ex[4][4];
    float rsum[4] = {0.f, 0.f, 0.f, 0.f};
    const float* mbase = mask + ((size_t)(b * GG + g0 + rbase)) * PP + w * 64 + lm;
#pragma unroll
    for (int pt = 0; pt < 4; ++pt)
#pragma unroll
        for (int r = 0; r < 4; ++r) {
            float s = acc[pt][r] * 0.0625f;              // 1/sqrt(256)
            s = fminf(9.f, fmaxf(-9.f, s));              // tanh saturation clamp
            const float e2 = __expf(2.f * s);
            const float th = (e2 - 1.f) / (e2 + 1.f);    // tanh(s)
            const float sc = 10.f * th + mbase[(size_t)r * PP + pt * 16];
            const float e = __expf(sc);                  // bounded: e^10 max
            ex[pt][r] = e;
            rsum[r] += e;
        }

    // reduce rsum over the 16 lanes of this quad (each owns this wave's 64 p)
#pragma unroll
    for (int r = 0; r < 4; ++r) {
#pragma unroll
        for (int mm = 1; mm < 16; mm <<= 1) rsum[r] += __shfl_xor(rsum[r], mm);
    }
    if (lm == 0) {
#pragma unroll
        for (int r = 0; r < 4; ++r) swsum[w][rbase + r] = rsum[r];
    }
    __syncthreads();

    float inv[4];
#pragma unroll
    for (int r = 0; r < 4; ++r) {
        float tot = 0.f;
#pragma unroll
        for (int wv = 0; wv < 8; ++wv) tot += swsum[wv][rbase + r];
        inv[r] = 1.f / tot;
    }

    float* obase = out + ((size_t)(b * GG + g0 + rbase)) * PP + w * 64 + lm;
#pragma unroll
    for (int pt = 0; pt < 4; ++pt)
#pragma unroll
        for (int r = 0; r < 4; ++r)
            obase[(size_t)r * PP + pt * 16] = ex[pt][r] * inv[r];
}

// ---------------------------------------------------------------------------
extern "C" void kernel_launch(void* const* d_in, const int* in_sizes, int n_in,
                              void* d_out, int out_size, void* d_ws, size_t ws_size,
                              hipStream_t stream)
{
    const float* in1  = (const float*)d_in[0];
    const float* in2  = (const float*)d_in[1];
    const float* ct   = (const float*)d_in[2];
    const float* mask = (const float*)d_in[3];
    const float* enc  = (const float*)d_in[4];
    const float* Wq   = (const float*)d_in[5];
    const float* Wk   = (const float*)d_in[6];
    const float* Wv   = (const float*)d_in[7];
    const float* Wcw  = (const float*)d_in[8];
    const float* Wcb  = (const float*)d_in[9];
    float* out = (float*)d_out;
    float* ws  = (float*)d_ws;

    const size_t SEG = (size_t)BB * GG * HK;  // 2M elements; 32 MB total ws
    __bf16* Khi = (__bf16*)ws;
    __bf16* Klo = Khi + SEG;
    __bf16* Vt  = (__bf16*)(ws + SEG);
    __bf16* Ath = Vt + SEG;
    __bf16* Qhi = (__bf16*)(ws + 2 * SEG);
    __bf16* Qlo = Qhi + SEG;
    __bf16* wkt_h = (__bf16*)(ws + 3 * SEG);
    __bf16* wkt_l = wkt_h + 65536;
    __bf16* wvt_h = wkt_l + 65536;
    __bf16* wvt_l = wvt_h + 65536;
    __bf16* wqt_h = wvt_l + 65536;
    __bf16* wqt_l = wqt_h + 131072;
    __bf16* wct_h = wqt_l + 131072;
    __bf16* wct_l = wct_h + 65536;
    __bf16* Atl   = (__bf16*)(ws + 3 * SEG) + 1048576;
    __bf16* mh_h  = (__bf16*)ws;
    __bf16* mh_l  = mh_h + SEG;
    __bf16* enc_h = (__bf16*)(ws + 2 * SEG);
    __bf16* enc_l = enc_h + SEG;

    const dim3 blk(256);

    weight_prep<<<dim3(1280), blk, 0, stream>>>(Wk, Wv, Wq, Wcw,
                                                wkt_h, wkt_l, wvt_h, wvt_l,
                                                wqt_h, wqt_l, wct_h, wct_l);

    fused_proj<<<dim3(1024), blk, 0, stream>>>(enc, wkt_h, wkt_l, wvt_h, wvt_l,
                                               Khi, Klo, Vt,
                                               in1, in2, ct, wqt_h, wqt_l, Wq,
                                               Qhi, Qlo);

    attn_v8<<<dim3(GG / 32, HH / 4, BB), blk, 0, stream>>>(Qhi, Qlo, Khi, Klo, Vt, mask, Ath, Atl);

    fused_post<<<dim3(2560), blk, 0, stream>>>(Ath, Atl, wct_h, wct_l, Wcb,
                                               mh_h, mh_l, enc, enc_h, enc_l);

    pointer_v2<<<dim3(GG / 16, BB), dim3(512), 0, stream>>>(mh_h, mh_l, enc_h, enc_l, mask, out);
}

// Round 12
// 204.007 us; speedup vs baseline: 1.5668x; 1.0632x over previous
//
#include <hip/hip_runtime.h>
#include <math.h>

#define BB 16
#define GG 512
#define PP 512
#define EE 256
#define HH 16
#define KD 16
#define HK 256

typedef __bf16 bf16x8 __attribute__((ext_vector_type(8)));
typedef __bf16 bf16x4 __attribute__((ext_vector_type(4)));
typedef float f32x4 __attribute__((ext_vector_type(4)));
typedef float f32x16 __attribute__((ext_vector_type(16)));

// LDS geometry for fused_proj (bytes): compute phase 30720, epilogue 29184.
#define SA_STRIDE 40           // 32 cols + 8 pad (80B rows: 16B-aligned, <=4-way banks)
#define SMEM_BYTES 30720

__device__ inline void cvt_split8(const float* __restrict__ p, bf16x8& h, bf16x8& l)
{
    float4 f0 = *(const float4*)p;
    float4 f1 = *(const float4*)(p + 4);
    float v[8] = {f0.x, f0.y, f0.z, f0.w, f1.x, f1.y, f1.z, f1.w};
#pragma unroll
    for (int j = 0; j < 8; ++j) {
        __bf16 hh = (__bf16)v[j];
        h[j] = hh;
        l[j] = (__bf16)(v[j] - (float)hh);
    }
}

// ---------------------------------------------------------------------------
// All four weight transpose+splits in one launch.
// ---------------------------------------------------------------------------
__global__ __launch_bounds__(256) void weight_prep(const float* __restrict__ Wk,
                                                   const float* __restrict__ Wv,
                                                   const float* __restrict__ Wq,
                                                   const float* __restrict__ Wc,
                                                   __bf16* __restrict__ wkt_h, __bf16* __restrict__ wkt_l,
                                                   __bf16* __restrict__ wvt_h, __bf16* __restrict__ wvt_l,
                                                   __bf16* __restrict__ wqt_h, __bf16* __restrict__ wqt_l,
                                                   __bf16* __restrict__ wct_h, __bf16* __restrict__ wct_l)
{
    int id = blockIdx.x * 256 + threadIdx.x;
    const float* W;
    __bf16 *th, *tl;
    int kbits;
    if (id < 65536)       { W = Wk; th = wkt_h; tl = wkt_l; kbits = 8; }
    else if (id < 131072) { id -= 65536;  W = Wv; th = wvt_h; tl = wvt_l; kbits = 8; }
    else if (id < 262144) { id -= 131072; W = Wq; th = wqt_h; tl = wqt_l; kbits = 9; }
    else                  { id -= 262144; W = Wc; th = wct_h; tl = wct_l; kbits = 8; }
    const int Kd = 1 << kbits;
    const int k = id & (Kd - 1);
    const int n = id >> kbits;
    const float v = W[(size_t)k * HK + n];
    const __bf16 h = (__bf16)v;
    th[((size_t)n << kbits) + k] = h;
    tl[((size_t)n << kbits) + k] = (__bf16)(v - (float)h);
}

// ---------------------------------------------------------------------------
// LDS-staged fused K/V projection body (verified round 10).
// ---------------------------------------------------------------------------
__device__ inline void kvproj_body(int bx, int tid, unsigned char* smem,
                                   const float* __restrict__ A,
                                   const __bf16* __restrict__ Bkh,
                                   const __bf16* __restrict__ Bkl,
                                   const __bf16* __restrict__ Bvh,
                                   const __bf16* __restrict__ Bvl,
                                   __bf16* __restrict__ Khi,
                                   __bf16* __restrict__ Klo,
                                   __bf16* __restrict__ Vt)
{
    __bf16* sAh = (__bf16*)smem;               // [64][SA_STRIDE]
    __bf16* sAl = sAh + 64 * SA_STRIDE;
    __bf16* sB  = sAl + 64 * SA_STRIDE;        // [4][64][SA_STRIDE]

    const int lane = tid & 63;
    const int w = __builtin_amdgcn_readfirstlane(tid >> 6);
    const int m0 = (bx >> 2) * 64;
    const int n0 = (bx & 3) * 64;
    const int wm = (w >> 1) * 32, wn = (w & 1) * 32;
    const int ln = lane & 15, kq = (lane >> 4) * 8;
    const int ar = tid >> 2, ac = (tid & 3) * 8;

    const __bf16* bsel = (w == 0) ? Bkh : (w == 1) ? Bkl : (w == 2) ? Bvh : Bvl;

    f32x4 ak[2][2], av[2][2];
#pragma unroll
    for (int i = 0; i < 2; ++i)
#pragma unroll
        for (int j = 0; j < 2; ++j) {
            ak[i][j] = (f32x4){0.f, 0.f, 0.f, 0.f};
            av[i][j] = (f32x4){0.f, 0.f, 0.f, 0.f};
        }

    for (int k0 = 0; k0 < EE; k0 += 32) {
        {
            bf16x8 h8, l8;
            cvt_split8(A + (size_t)(m0 + ar) * EE + k0 + ac, h8, l8);
            *(bf16x8*)&sAh[ar * SA_STRIDE + ac] = h8;
            *(bf16x8*)&sAl[ar * SA_STRIDE + ac] = l8;
        }
        {
            const __bf16* src = bsel + (size_t)(n0 + lane) * EE + k0;
            __bf16* dst = sB + (w * 64 + lane) * SA_STRIDE;
            *(bf16x8*)&dst[0]  = *(const bf16x8*)&src[0];
            *(bf16x8*)&dst[8]  = *(const bf16x8*)&src[8];
            *(bf16x8*)&dst[16] = *(const bf16x8*)&src[16];
            *(bf16x8*)&dst[24] = *(const bf16x8*)&src[24];
        }
        __syncthreads();

        bf16x8 ah[2], al[2];
#pragma unroll
        for (int mt = 0; mt < 2; ++mt) {
            ah[mt] = *(const bf16x8*)&sAh[(wm + mt * 16 + ln) * SA_STRIDE + kq];
            al[mt] = *(const bf16x8*)&sAl[(wm + mt * 16 + ln) * SA_STRIDE + kq];
        }
#pragma unroll
        for (int nt = 0; nt < 2; ++nt) {
            const int rowb = wn + nt * 16 + ln;
            bf16x8 bkh8 = *(const bf16x8*)&sB[(0 * 64 + rowb) * SA_STRIDE + kq];
            bf16x8 bkl8 = *(const bf16x8*)&sB[(1 * 64 + rowb) * SA_STRIDE + kq];
            bf16x8 bvh8 = *(const bf16x8*)&sB[(2 * 64 + rowb) * SA_STRIDE + kq];
            bf16x8 bvl8 = *(const bf16x8*)&sB[(3 * 64 + rowb) * SA_STRIDE + kq];
#pragma unroll
            for (int mt = 0; mt < 2; ++mt) {
                ak[mt][nt] = __builtin_amdgcn_mfma_f32_16x16x32_bf16(ah[mt], bkh8, ak[mt][nt], 0, 0, 0);
                ak[mt][nt] = __builtin_amdgcn_mfma_f32_16x16x32_bf16(al[mt], bkh8, ak[mt][nt], 0, 0, 0);
                ak[mt][nt] = __builtin_amdgcn_mfma_f32_16x16x32_bf16(ah[mt], bkl8, ak[mt][nt], 0, 0, 0);
                av[mt][nt] = __builtin_amdgcn_mfma_f32_16x16x32_bf16(ah[mt], bvh8, av[mt][nt], 0, 0, 0);
                av[mt][nt] = __builtin_amdgcn_mfma_f32_16x16x32_bf16(al[mt], bvh8, av[mt][nt], 0, 0, 0);
                av[mt][nt] = __builtin_amdgcn_mfma_f32_16x16x32_bf16(ah[mt], bvl8, av[mt][nt], 0, 0, 0);
            }
        }
        __syncthreads();
    }

    __bf16* eKh = (__bf16*)smem;
    __bf16* eKl = eKh + 5120;
    __bf16* eV  = eKl + 5120;

    const int rbase = (lane >> 4) * 4;
#pragma unroll
    for (int mt = 0; mt < 2; ++mt)
#pragma unroll
        for (int nt = 0; nt < 2; ++nt) {
            const int hloc = (w & 1) * 2 + nt;
            const int nl = wn + nt * 16 + ln;
#pragma unroll
            for (int r = 0; r < 4; ++r) {
                const int m = wm + mt * 16 + rbase + r;
                const float vk = ak[mt][nt][r];
                const __bf16 hk = (__bf16)vk;
                eKh[(hloc * 64 + m) * 20 + ln] = hk;
                eKl[(hloc * 64 + m) * 20 + ln] = (__bf16)(vk - (float)hk);
                eV[nl * 68 + m] = (__bf16)av[mt][nt][r];
            }
        }
    __syncthreads();

    const int b = m0 >> 9;
    const int pbase = m0 & (PP - 1);
    {
        const int hl = tid >> 6, p = tid & 63;
        const int hg = (n0 >> 4) + hl;
        const size_t dst = (((size_t)b * HH + hg) * PP + pbase + p) * KD;
        const int base = (hl * 64 + p) * 20;
        uint2 a0 = *(const uint2*)&eKh[base + 0];
        uint2 a1 = *(const uint2*)&eKh[base + 4];
        uint2 a2 = *(const uint2*)&eKh[base + 8];
        uint2 a3 = *(const uint2*)&eKh[base + 12];
        *(uint4*)(Khi + dst)     = make_uint4(a0.x, a0.y, a1.x, a1.y);
        *(uint4*)(Khi + dst + 8) = make_uint4(a2.x, a2.y, a3.x, a3.y);
        uint2 c0 = *(const uint2*)&eKl[base + 0];
        uint2 c1 = *(const uint2*)&eKl[base + 4];
        uint2 c2 = *(const uint2*)&eKl[base + 8];
        uint2 c3 = *(const uint2*)&eKl[base + 12];
        *(uint4*)(Klo + dst)     = make_uint4(c0.x, c0.y, c1.x, c1.y);
        *(uint4*)(Klo + dst + 8) = make_uint4(c2.x, c2.y, c3.x, c3.y);
    }
    {
        const int n = tid >> 2, qq = tid & 3;
        const int ng = n0 + n, hg = ng >> 4, kk = ng & 15;
        const int base = n * 68 + qq * 16;
        uint2 v0 = *(const uint2*)&eV[base + 0];
        uint2 v1 = *(const uint2*)&eV[base + 4];
        uint2 v2 = *(const uint2*)&eV[base + 8];
        uint2 v3 = *(const uint2*)&eV[base + 12];
        const size_t dst = ((((size_t)b * HH + hg) * KD + kk) * PP) + pbase + qq * 16;
        *(uint4*)(Vt + dst)     = make_uint4(v0.x, v0.y, v1.x, v1.y);
        *(uint4*)(Vt + dst + 8) = make_uint4(v2.x, v2.y, v3.x, v3.y);
    }
}

// ---------------------------------------------------------------------------
// LDS-staged Q projection body (verified round 10).
// ---------------------------------------------------------------------------
__device__ inline void qproj_body(int bx, int tid, unsigned char* smem,
                                  const float* __restrict__ in1,
                                  const float* __restrict__ in2,
                                  const float* __restrict__ ct,
                                  const __bf16* __restrict__ Bh,
                                  const __bf16* __restrict__ Bl,
                                  const float* __restrict__ WqFull,
                                  __bf16* __restrict__ Qhi,
                                  __bf16* __restrict__ Qlo)
{
    __bf16* sAh = (__bf16*)smem;
    __bf16* sAl = sAh + 64 * SA_STRIDE;
    __bf16* sB  = sAl + 64 * SA_STRIDE;

    const int lane = tid & 63;
    const int w = __builtin_amdgcn_readfirstlane(tid >> 6);
    const int m0 = (bx >> 2) * 64;
    const int n0 = (bx & 3) * 64;
    const int wm = (w >> 1) * 32, wn = (w & 1) * 32;
    const int ln = lane & 15, kq = (lane >> 4) * 8;
    const int ar = tid >> 2, ac = (tid & 3) * 8;
    const int b = m0 >> 9;
    const float* WqLast = WqFull + (size_t)512 * HK;

    f32x4 acc[2][2];
#pragma unroll
    for (int i = 0; i < 2; ++i)
#pragma unroll
        for (int j = 0; j < 2; ++j) acc[i][j] = (f32x4){0.f, 0.f, 0.f, 0.f};

    for (int k0 = 0; k0 < 512; k0 += 32) {
        {
            const float* ap = (k0 < 256)
                ? in1 + (size_t)b * EE + k0 + ac
                : in2 + (size_t)(m0 + ar) * EE + (k0 - 256) + ac;
            bf16x8 h8, l8;
            cvt_split8(ap, h8, l8);
            *(bf16x8*)&sAh[ar * SA_STRIDE + ac] = h8;
            *(bf16x8*)&sAl[ar * SA_STRIDE + ac] = l8;
        }
        {
            const int mat = w >> 1;
            const int row = (w & 1) * 32 + (lane >> 1);
            const int half = (lane & 1) * 16;
            const __bf16* src = (mat ? Bl : Bh) + ((size_t)(n0 + row) << 9) + k0 + half;
            __bf16* dst = sB + (mat * 64 + row) * SA_STRIDE + half;
            *(bf16x8*)&dst[0] = *(const bf16x8*)&src[0];
            *(bf16x8*)&dst[8] = *(const bf16x8*)&src[8];
        }
        __syncthreads();

        bf16x8 ah[2], al[2];
#pragma unroll
        for (int mt = 0; mt < 2; ++mt) {
            ah[mt] = *(const bf16x8*)&sAh[(wm + mt * 16 + ln) * SA_STRIDE + kq];
            al[mt] = *(const bf16x8*)&sAl[(wm + mt * 16 + ln) * SA_STRIDE + kq];
        }
#pragma unroll
        for (int nt = 0; nt < 2; ++nt) {
            const int rowb = wn + nt * 16 + ln;
            bf16x8 bh8 = *(const bf16x8*)&sB[(0 * 64 + rowb) * SA_STRIDE + kq];
            bf16x8 bl8 = *(const bf16x8*)&sB[(1 * 64 + rowb) * SA_STRIDE + kq];
#pragma unroll
            for (int mt = 0; mt < 2; ++mt) {
                acc[mt][nt] = __builtin_amdgcn_mfma_f32_16x16x32_bf16(ah[mt], bh8, acc[mt][nt], 0, 0, 0);
                acc[mt][nt] = __builtin_amdgcn_mfma_f32_16x16x32_bf16(al[mt], bh8, acc[mt][nt], 0, 0, 0);
                acc[mt][nt] = __builtin_amdgcn_mfma_f32_16x16x32_bf16(ah[mt], bl8, acc[mt][nt], 0, 0, 0);
            }
        }
        __syncthreads();
    }

    __bf16* eQh = (__bf16*)smem;
    __bf16* eQl = eQh + 5120;

    const int rbase = (lane >> 4) * 4;
#pragma unroll
    for (int mt = 0; mt < 2; ++mt)
#pragma unroll
        for (int nt = 0; nt < 2; ++nt) {
            const int hloc = (w & 1) * 2 + nt;
            const int ng = n0 + wn + nt * 16 + ln;
            const float wq = WqLast[ng];
#pragma unroll
            for (int r = 0; r < 4; ++r) {
                const int m = wm + mt * 16 + rbase + r;
                const float v = acc[mt][nt][r] + ct[m0 + m] * wq;
                const __bf16 h = (__bf16)v;
                eQh[(hloc * 64 + m) * 20 + ln] = h;
                eQl[(hloc * 64 + m) * 20 + ln] = (__bf16)(v - (float)h);
            }
        }
    __syncthreads();

    {
        const int hl = tid >> 6, p = tid & 63;
        const int hg = (n0 >> 4) + hl;
        const int g = (m0 & (GG - 1)) + p;
        const size_t dst = (((size_t)b * HH + hg) * GG + g) * KD;
        const int base = (hl * 64 + p) * 20;
        uint2 a0 = *(const uint2*)&eQh[base + 0];
        uint2 a1 = *(const uint2*)&eQh[base + 4];
        uint2 a2 = *(const uint2*)&eQh[base + 8];
        uint2 a3 = *(const uint2*)&eQh[base + 12];
        *(uint4*)(Qhi + dst)     = make_uint4(a0.x, a0.y, a1.x, a1.y);
        *(uint4*)(Qhi + dst + 8) = make_uint4(a2.x, a2.y, a3.x, a3.y);
        uint2 c0 = *(const uint2*)&eQl[base + 0];
        uint2 c1 = *(const uint2*)&eQl[base + 4];
        uint2 c2 = *(const uint2*)&eQl[base + 8];
        uint2 c3 = *(const uint2*)&eQl[base + 12];
        *(uint4*)(Qlo + dst)     = make_uint4(c0.x, c0.y, c1.x, c1.y);
        *(uint4*)(Qlo + dst + 8) = make_uint4(c2.x, c2.y, c3.x, c3.y);
    }
}

// ---------------------------------------------------------------------------
// Fused K/V + Q projections: 1024 blocks.
// ---------------------------------------------------------------------------
__global__ __launch_bounds__(256, 2) void fused_proj(const float* __restrict__ enc,
                                                     const __bf16* __restrict__ Bkh,
                                                     const __bf16* __restrict__ Bkl,
                                                     const __bf16* __restrict__ Bvh,
                                                     const __bf16* __restrict__ Bvl,
                                                     __bf16* __restrict__ Khi,
                                                     __bf16* __restrict__ Klo,
                                                     __bf16* __restrict__ Vt,
                                                     const float* __restrict__ in1,
                                                     const float* __restrict__ in2,
                                                     const float* __restrict__ ct,
                                                     const __bf16* __restrict__ Bqh,
                                                     const __bf16* __restrict__ Bql,
                                                     const float* __restrict__ WqFull,
                                                     __bf16* __restrict__ Qhi,
                                                     __bf16* __restrict__ Qlo)
{
    __shared__ __align__(16) unsigned char smem[SMEM_BYTES];
    const int id = blockIdx.x;
    if (id < 512)
        kvproj_body(id, threadIdx.x, smem, enc, Bkh, Bkl, Bvh, Bvl, Khi, Klo, Vt);
    else
        qproj_body(id - 512, threadIdx.x, smem, in1, in2, ct, Bqh, Bql, WqFull, Qhi, Qlo);
}

// ---------------------------------------------------------------------------
// attn_v8 (verified round 8): one wave per (b, h, 32 g); 32x32x16 QK,
// sum-only flash, per-wave LDS P staging, 16x16x32 PV; bf16 hi/lo output.
// ---------------------------------------------------------------------------
__global__ __launch_bounds__(256, 4) void attn_v8(const __bf16* __restrict__ Qhi,
                                                  const __bf16* __restrict__ Qlo,
                                                  const __bf16* __restrict__ Khi,
                                                  const __bf16* __restrict__ Klo,
                                                  const __bf16* __restrict__ Vt,
                                                  const float* __restrict__ mask,
                                                  __bf16* __restrict__ Ath,
                                                  __bf16* __restrict__ Atl)
{
    __shared__ __align__(16) __bf16 sP[4][32][40];
    __shared__ float srs[4][32];

    const int t = threadIdx.x;
    const int lane = t & 63;
    const int w = __builtin_amdgcn_readfirstlane(t >> 6);
    const int g0 = blockIdx.x * 32;
    const int h = blockIdx.y * 4 + w;
    const int b = blockIdx.z;
    const int ln32 = lane & 31;
    const int half = lane >> 5;
    const int ln16 = lane & 15;
    const int quad = (lane >> 4) & 3;

    const size_t qbase = (((size_t)b * HH + h) * GG + g0) * KD;
    const size_t kbase = ((size_t)b * HH + h) * PP * KD;
    const size_t vbase = ((size_t)b * HH + h) * KD * PP;
    const float* mbase = mask + ((size_t)(b * GG + g0)) * PP;

    bf16x8 qah = *(const bf16x8*)(Qhi + qbase + (size_t)ln32 * KD + half * 8);
    bf16x8 qal = *(const bf16x8*)(Qlo + qbase + (size_t)ln32 * KD + half * 8);

    float rs[16];
#pragma unroll
    for (int r = 0; r < 16; ++r) rs[r] = 0.f;
    f32x4 o0 = (f32x4){0.f, 0.f, 0.f, 0.f};
    f32x4 o1 = (f32x4){0.f, 0.f, 0.f, 0.f};

#pragma unroll 2
    for (int pc = 0; pc < 16; ++pc) {
        const int pb = pc * 32;
        const size_t ko = kbase + (size_t)(pb + ln32) * KD + half * 8;
        bf16x8 kh = *(const bf16x8*)(Khi + ko);
        bf16x8 kl = *(const bf16x8*)(Klo + ko);

        f32x16 s = (f32x16){0.f, 0.f, 0.f, 0.f, 0.f, 0.f, 0.f, 0.f,
                            0.f, 0.f, 0.f, 0.f, 0.f, 0.f, 0.f, 0.f};
        s = __builtin_amdgcn_mfma_f32_32x32x16_bf16(qah, kh, s, 0, 0, 0);
        s = __builtin_amdgcn_mfma_f32_32x32x16_bf16(qal, kh, s, 0, 0, 0);
        s = __builtin_amdgcn_mfma_f32_32x32x16_bf16(qah, kl, s, 0, 0, 0);

#pragma unroll
        for (int r = 0; r < 16; ++r) {
            const int row = (r & 3) + 8 * (r >> 2) + 4 * half;
            const float m = mbase[(size_t)row * PP + pb + ln32];
            const float e = __expf(s[r] * 0.25f + m);
            rs[r] += e;
            sP[w][row][ln32] = (__bf16)e;
        }

        bf16x8 vb = *(const bf16x8*)(Vt + vbase + (size_t)ln16 * PP + pb + quad * 8);
        bf16x8 p0 = *(const bf16x8*)&sP[w][ln16][quad * 8];
        bf16x8 p1 = *(const bf16x8*)&sP[w][16 + ln16][quad * 8];
        o0 = __builtin_amdgcn_mfma_f32_16x16x32_bf16(p0, vb, o0, 0, 0, 0);
        o1 = __builtin_amdgcn_mfma_f32_16x16x32_bf16(p1, vb, o1, 0, 0, 0);
    }

#pragma unroll
    for (int r = 0; r < 16; ++r) {
#pragma unroll
        for (int mm = 1; mm < 32; mm <<= 1) rs[r] += __shfl_xor(rs[r], mm);
    }
    if (ln32 == 0) {
#pragma unroll
        for (int r = 0; r < 16; ++r)
            srs[w][(r & 3) + 8 * (r >> 2) + 4 * half] = rs[r];
    }

#pragma unroll
    for (int t2 = 0; t2 < 2; ++t2) {
        const f32x4 oc = t2 ? o1 : o0;
#pragma unroll
        for (int r = 0; r < 4; ++r) {
            const int grow = t2 * 16 + quad * 4 + r;
            const float v = oc[r] / srs[w][grow];
            const __bf16 hv = (__bf16)v;
            const size_t oo = ((size_t)(b * GG + g0 + grow)) * HK + h * KD + ln16;
            Ath[oo] = hv;
            Atl[oo] = (__bf16)(v - (float)hv);
        }
    }
}

// ---------------------------------------------------------------------------
// Fused post-attention: outproj (512 blocks) + enc prep_split (2048 blocks).
// ---------------------------------------------------------------------------
__device__ inline void outproj_body(int bx, int tid,
                                    const __bf16* __restrict__ Ah,
                                    const __bf16* __restrict__ Al,
                                    const __bf16* __restrict__ Bh,
                                    const __bf16* __restrict__ Bl,
                                    const float* __restrict__ bias,
                                    __bf16* __restrict__ Ch,
                                    __bf16* __restrict__ Cl)
{
    const int lane = tid & 63, w = tid >> 6;
    const int m0 = (bx >> 2) * 64 + (w >> 1) * 32;
    const int n0 = (bx & 3) * 64 + (w & 1) * 32;
    const int ln = lane & 15, kc = (lane >> 4) * 8;

    f32x4 acc[2][2];
#pragma unroll
    for (int i = 0; i < 2; ++i)
#pragma unroll
        for (int j = 0; j < 2; ++j) acc[i][j] = (f32x4){0.f, 0.f, 0.f, 0.f};

    for (int k0 = 0; k0 < EE; k0 += 32) {
        bf16x8 ah[2], al[2], bh[2], bl[2];
#pragma unroll
        for (int mt = 0; mt < 2; ++mt) {
            const size_t o = (size_t)(m0 + mt * 16 + ln) * EE + k0 + kc;
            ah[mt] = *(const bf16x8*)(Ah + o);
            al[mt] = *(const bf16x8*)(Al + o);
        }
#pragma unroll
        for (int nt = 0; nt < 2; ++nt) {
            const size_t o = (size_t)(n0 + nt * 16 + ln) * EE + k0 + kc;
            bh[nt] = *(const bf16x8*)(Bh + o);
            bl[nt] = *(const bf16x8*)(Bl + o);
        }
#pragma unroll
        for (int mt = 0; mt < 2; ++mt)
#pragma unroll
            for (int nt = 0; nt < 2; ++nt) {
                acc[mt][nt] = __builtin_amdgcn_mfma_f32_16x16x32_bf16(ah[mt], bh[nt], acc[mt][nt], 0, 0, 0);
                acc[mt][nt] = __builtin_amdgcn_mfma_f32_16x16x32_bf16(al[mt], bh[nt], acc[mt][nt], 0, 0, 0);
                acc[mt][nt] = __builtin_amdgcn_mfma_f32_16x16x32_bf16(ah[mt], bl[nt], acc[mt][nt], 0, 0, 0);
            }
    }

    const int rbase = (lane >> 4) * 4;
#pragma unroll
    for (int mt = 0; mt < 2; ++mt)
#pragma unroll
        for (int nt = 0; nt < 2; ++nt)
#pragma unroll
            for (int r = 0; r < 4; ++r) {
                const int m = m0 + rbase + r + mt * 16;
                const int n = n0 + nt * 16 + ln;
                const float v = acc[mt][nt][r] + bias[n];
                const __bf16 h = (__bf16)v;
                Ch[(size_t)m * HK + n] = h;
                Cl[(size_t)m * HK + n] = (__bf16)(v - (float)h);
            }
}

__global__ __launch_bounds__(256) void fused_post(const __bf16* __restrict__ Ah,
                                                  const __bf16* __restrict__ Al,
                                                  const __bf16* __restrict__ Bh,
                                                  const __bf16* __restrict__ Bl,
                                                  const float* __restrict__ bias,
                                                  __bf16* __restrict__ Ch,
                                                  __bf16* __restrict__ Cl,
                                                  const float* __restrict__ enc,
                                                  __bf16* __restrict__ enc_h,
                                                  __bf16* __restrict__ enc_l)
{
    const int id = blockIdx.x;
    if (id < 512) {
        outproj_body(id, threadIdx.x, Ah, Al, Bh, Bl, bias, Ch, Cl);
    } else {
        const int i = ((id - 512) * 256 + threadIdx.x) * 4;
        float4 v = *(const float4*)(enc + i);
        bf16x4 h, l;
        h[0] = (__bf16)v.x; l[0] = (__bf16)(v.x - (float)h[0]);
        h[1] = (__bf16)v.y; l[1] = (__bf16)(v.y - (float)h[1]);
        h[2] = (__bf16)v.z; l[2] = (__bf16)(v.z - (float)h[2]);
        h[3] = (__bf16)v.w; l[3] = (__bf16)(v.w - (float)h[3]);
        *(bf16x4*)(enc_h + i) = h;
        *(bf16x4*)(enc_l + i) = l;
    }
}

// ---------------------------------------------------------------------------
// Pointer head v3: 32x32x16 MFMA (2x MACs/inst vs 16x16x32), 32 g per block,
// XCD-pinned batches (b = blockIdx & 15 -> XCD = b%8 keeps enc[b] in one L2).
// 512 threads = 8 waves x 64 p. Register softmax (verified round 11).
// ---------------------------------------------------------------------------
__global__ __launch_bounds__(512) void pointer_v3(const __bf16* __restrict__ mh_hi,
                                                  const __bf16* __restrict__ mh_lo,
                                                  const __bf16* __restrict__ enc_hi,
                                                  const __bf16* __restrict__ enc_lo,
                                                  const float* __restrict__ mask,
                                                  float* __restrict__ out)
{
    __shared__ float swsum[8][32];
    const int t = threadIdx.x;
    const int lane = t & 63;
    const int w = __builtin_amdgcn_readfirstlane(t >> 6);  // 0..7, 64 p each
    const int id = blockIdx.x;
    const int b = id & 15;                 // XCD pin: id%8 == b%8
    const int g0 = (id >> 4) * 32;
    const int ln32 = lane & 31;
    const int half = lane >> 5;

    // A-frag rows: g = g0 + ln32, k = kc + half*8.  B-frag rows: p.
    const size_t arow = ((size_t)(b * GG + g0 + ln32)) * EE + half * 8;
    const size_t brow = ((size_t)(b * PP + w * 64 + ln32)) * EE + half * 8;

    f32x16 acc[2];
#pragma unroll
    for (int pt = 0; pt < 2; ++pt)
        acc[pt] = (f32x16){0.f, 0.f, 0.f, 0.f, 0.f, 0.f, 0.f, 0.f,
                           0.f, 0.f, 0.f, 0.f, 0.f, 0.f, 0.f, 0.f};

    for (int kc = 0; kc < EE; kc += 16) {
        bf16x8 ah = *(const bf16x8*)(mh_hi + arow + kc);
        bf16x8 al = *(const bf16x8*)(mh_lo + arow + kc);
#pragma unroll
        for (int pt = 0; pt < 2; ++pt) {
            const size_t bo = brow + (size_t)pt * 32 * EE + kc;
            bf16x8 bh = *(const bf16x8*)(enc_hi + bo);
            bf16x8 bl = *(const bf16x8*)(enc_lo + bo);
            acc[pt] = __builtin_amdgcn_mfma_f32_32x32x16_bf16(ah, bh, acc[pt], 0, 0, 0);
            acc[pt] = __builtin_amdgcn_mfma_f32_32x32x16_bf16(al, bh, acc[pt], 0, 0, 0);
            acc[pt] = __builtin_amdgcn_mfma_f32_32x32x16_bf16(ah, bl, acc[pt], 0, 0, 0);
        }
    }

    // clip + mask + exp in registers; C/D row = (r&3)+8*(r>>2)+4*half, col p.
    float rsum[16];
#pragma unroll
    for (int r = 0; r < 16; ++r) rsum[r] = 0.f;
#pragma unroll
    for (int pt = 0; pt < 2; ++pt)
#pragma unroll
        for (int r = 0; r < 16; ++r) {
            const int row = (r & 3) + 8 * (r >> 2) + 4 * half;
            float s = acc[pt][r] * 0.0625f;              // 1/sqrt(256)
            s = fminf(9.f, fmaxf(-9.f, s));
            const float e2 = __expf(2.f * s);
            const float th = (e2 - 1.f) / (e2 + 1.f);    // tanh(s)
            const float m = mask[((size_t)(b * GG + g0 + row)) * PP + w * 64 + pt * 32 + ln32];
            const float e = __expf(10.f * th + m);       // bounded by e^10
            acc[pt][r] = e;
            rsum[r] += e;
        }

    // sum over the 32 p-columns within this half (rows differ across halves)
#pragma unroll
    for (int r = 0; r < 16; ++r) {
        rsum[r] += __shfl_xor(rsum[r], 1);
        rsum[r] += __shfl_xor(rsum[r], 2);
        rsum[r] += __shfl_xor(rsum[r], 4);
        rsum[r] += __shfl_xor(rsum[r], 8);
        rsum[r] += __shfl_xor(rsum[r], 16);
    }
    if (ln32 == 0) {
#pragma unroll
        for (int r = 0; r < 16; ++r)
            swsum[w][(r & 3) + 8 * (r >> 2) + 4 * half] = rsum[r];
    }
    __syncthreads();

    float inv[16];
#pragma unroll
    for (int r = 0; r < 16; ++r) {
        const int row = (r & 3) + 8 * (r >> 2) + 4 * half;
        float tot = 0.f;
#pragma unroll
        for (int wv = 0; wv < 8; ++wv) tot += swsum[wv][row];  // LDS broadcast
        inv[r] = 1.f / tot;
    }

#pragma unroll
    for (int pt = 0; pt < 2; ++pt)
#pragma unroll
        for (int r = 0; r < 16; ++r) {
            const int row = (r & 3) + 8 * (r >> 2) + 4 * half;
            out[((size_t)(b * GG + g0 + row)) * PP + w * 64 + pt * 32 + ln32] =
                acc[pt][r] * inv[r];
        }
}

// ---------------------------------------------------------------------------
extern "C" void kernel_launch(void* const* d_in, const int* in_sizes, int n_in,
                              void* d_out, int out_size, void* d_ws, size_t ws_size,
                              hipStream_t stream)
{
    const float* in1  = (const float*)d_in[0];
    const float* in2  = (const float*)d_in[1];
    const float* ct   = (const float*)d_in[2];
    const float* mask = (const float*)d_in[3];
    const float* enc  = (const float*)d_in[4];
    const float* Wq   = (const float*)d_in[5];
    const float* Wk   = (const float*)d_in[6];
    const float* Wv   = (const float*)d_in[7];
    const float* Wcw  = (const float*)d_in[8];
    const float* Wcb  = (const float*)d_in[9];
    float* out = (float*)d_out;
    float* ws  = (float*)d_ws;

    const size_t SEG = (size_t)BB * GG * HK;  // 2M elements; 32 MB total ws
    __bf16* Khi = (__bf16*)ws;
    __bf16* Klo = Khi + SEG;
    __bf16* Vt  = (__bf16*)(ws + SEG);
    __bf16* Ath = Vt + SEG;
    __bf16* Qhi = (__bf16*)(ws + 2 * SEG);
    __bf16* Qlo = Qhi + SEG;
    __bf16* wkt_h = (__bf16*)(ws + 3 * SEG);
    __bf16* wkt_l = wkt_h + 65536;
    __bf16* wvt_h = wkt_l + 65536;
    __bf16* wvt_l = wvt_h + 65536;
    __bf16* wqt_h = wvt_l + 65536;
    __bf16* wqt_l = wqt_h + 131072;
    __bf16* wct_h = wqt_l + 131072;
    __bf16* wct_l = wct_h + 65536;
    __bf16* Atl   = (__bf16*)(ws + 3 * SEG) + 1048576;
    __bf16* mh_h  = (__bf16*)ws;
    __bf16* mh_l  = mh_h + SEG;
    __bf16* enc_h = (__bf16*)(ws + 2 * SEG);
    __bf16* enc_l = enc_h + SEG;

    const dim3 blk(256);

    weight_prep<<<dim3(1280), blk, 0, stream>>>(Wk, Wv, Wq, Wcw,
                                                wkt_h, wkt_l, wvt_h, wvt_l,
                                                wqt_h, wqt_l, wct_h, wct_l);

    fused_proj<<<dim3(1024), blk, 0, stream>>>(enc, wkt_h, wkt_l, wvt_h, wvt_l,
                                               Khi, Klo, Vt,
                                               in1, in2, ct, wqt_h, wqt_l, Wq,
                                               Qhi, Qlo);

    attn_v8<<<dim3(GG / 32, HH / 4, BB), blk, 0, stream>>>(Qhi, Qlo, Khi, Klo, Vt, mask, Ath, Atl);

    fused_post<<<dim3(2560), blk, 0, stream>>>(Ath, Atl, wct_h, wct_l, Wcb,
                                               mh_h, mh_l, enc, enc_h, enc_l);

    pointer_v3<<<dim3(256), dim3(512), 0, stream>>>(mh_h, mh_l, enc_h, enc_l, mask, out);
}